// Round 10
// baseline (1111.295 us; speedup 1.0000x reference)
//
#include <hip/hip_runtime.h>
#include <hip/hip_bf16.h>

// GIN 2-layer forward — R10: R8 base (fusion reverted — twice failed: R6
// occupancy, R9 grid-size), + block_sum folded into degree atomics, +
// quarter-wave gather_d128 (4 neighbors in flight per wave).
//
//   memset(deg|bsum) -> prep (cvt x | transpose w1/w2/w3 | degree+bsum atomics)
//   scan_blocks2 -> fill
//   h1in  = x_bf + gather(x_bf)                     [bf16, stride 136]
//   h1    = relu(relu(h1in@w1+b1)@w2+b2)            [layer1_fused, t1 in LDS only]
//   h2in  = h1 + gather(h1)                         [bf16, stride 264]
//   out   = log_softmax(relu(h2in@w3+b3)@w4+b4)     [layer2_fused, t2 in LDS only]

typedef __attribute__((ext_vector_type(8))) short bf16x8;
typedef __attribute__((ext_vector_type(4))) float f32x4;

static __device__ __forceinline__ unsigned short f2bf(float f) {
    unsigned int u = __float_as_uint(f);
    unsigned int r = (u + 0x7fffu + ((u >> 16) & 1u)) >> 16;
    return (unsigned short)r;
}
static __device__ __forceinline__ float bf2f(unsigned short s) {
    return __uint_as_float(((unsigned int)s) << 16);
}
static __device__ __forceinline__ float bflo(unsigned int u) {
    return __uint_as_float(u << 16);
}
static __device__ __forceinline__ float bfhi(unsigned int u) {
    return __uint_as_float(u & 0xffff0000u);
}

#define S1 136   // 128 + 8 pad (bf16 elems)
#define S2 264   // 256 + 8 pad

// ---------------- prep: cvt x | transpose w1/w2/w3 | degree(+bsum) ----------------
// deg[] and bsum[] must be zeroed (one memsetAsync) before this kernel runs.
__global__ __launch_bounds__(256) void prep_kernel(
    const float* __restrict__ x, short* __restrict__ x_bf,
    const float* __restrict__ w1, const float* __restrict__ w2, const float* __restrict__ w3,
    short* __restrict__ w1t, short* __restrict__ w2t, short* __restrict__ w3t,
    const int* __restrict__ dst, int* __restrict__ deg, int* __restrict__ bsum,
    int M, int E, int cB)
{
    const int b = blockIdx.x;
    const int t = threadIdx.x;
    if (b < cB) {
        // cvt x -> bf16, 4 elems/thread
        const int i = b * 256 + t;
        const int n4 = M * 32;   // M*128/4
        if (i >= n4) return;
        const float4 v = *(const float4*)(x + (size_t)i * 4);
        ushort4 o;
        o.x = f2bf(v.x); o.y = f2bf(v.y); o.z = f2bf(v.z); o.w = f2bf(v.w);
        *(ushort4*)(x_bf + (size_t)i * 4) = o;
        return;
    }
    if (b < cB + 192) {
        // transpose-convert: 192 blocks: z in [0,3), 8x8 (k,n) tiles of 32
        const int tb = b - cB;
        const int z = tb >> 6;
        const int rem = tb & 63;
        const int kb = rem & 7;
        const int nb = rem >> 3;
        const float* in; short* outb; int K, ostride;
        if (z == 0)      { in = w1; outb = w1t; K = 128; ostride = S1; }
        else if (z == 1) { in = w2; outb = w2t; K = 256; ostride = S2; }
        else             { in = w3; outb = w3t; K = 256; ostride = S2; }
        const int N = 256;
        const int k0 = kb * 32;
        if (k0 >= K) return;
        const int n0 = nb * 32;
        __shared__ float tile[32][33];
        const int tx = t & 31;
        const int ty = t >> 5;   // 0..7
        #pragma unroll
        for (int i = 0; i < 4; ++i)
            tile[ty + 8 * i][tx] = in[(size_t)(k0 + ty + 8 * i) * N + n0 + tx];
        __syncthreads();
        #pragma unroll
        for (int i = 0; i < 4; ++i)
            outb[(size_t)(n0 + ty + 8 * i) * ostride + k0 + tx] = (short)f2bf(tile[tx][ty + 8 * i]);
        return;
    }
    // degree + per-1024-chunk sums (block_sum folded in)
    const int e = (b - cB - 192) * 256 + t;
    if (e < E) {
        const int d = dst[e];
        atomicAdd(&deg[d], 1);
        atomicAdd(&bsum[d >> 10], 1);
    }
}

// scan_partials fused in: every block wave-scans the <=64 bsum entries itself.
__global__ __launch_bounds__(256) void scan_blocks2_kernel(
    const int* __restrict__ deg, const int* __restrict__ bsum,
    int* __restrict__ rowptr, int* __restrict__ cur, int M, int E, int nB)
{
    const int b = blockIdx.x, t = threadIdx.x;
    __shared__ int sboff;
    if (t < 64) {
        const int v = (t < nB) ? bsum[t] : 0;
        int inc = v;
        #pragma unroll
        for (int off = 1; off < 64; off <<= 1) {
            const int u = __shfl_up(inc, off);
            if (t >= off) inc += u;
        }
        const int prev = __shfl(inc, (b == 0) ? 0 : (b - 1));
        if (t == 0) sboff = (b == 0) ? 0 : prev;
    }
    const int idx = b * 1024 + t * 4;
    int4 d = make_int4(0, 0, 0, 0);
    if (idx + 3 < M) {
        d = *(const int4*)(deg + idx);
    } else {
        if (idx + 0 < M) d.x = deg[idx + 0];
        if (idx + 1 < M) d.y = deg[idx + 1];
        if (idx + 2 < M) d.z = deg[idx + 2];
        if (idx + 3 < M) d.w = deg[idx + 3];
    }
    const int tot = d.x + d.y + d.z + d.w;
    const int lane = t & 63, wid = t >> 6;
    int inc = tot;
    #pragma unroll
    for (int off = 1; off < 64; off <<= 1) {
        const int u = __shfl_up(inc, off);
        if (lane >= off) inc += u;
    }
    __shared__ int wsum[4];
    if (lane == 63) wsum[wid] = inc;
    __syncthreads();
    int woff = 0;
    #pragma unroll
    for (int w = 0; w < 4; ++w) if (w < wid) woff += wsum[w];
    int p = sboff + woff + (inc - tot);
    if (idx + 0 < M) { rowptr[idx + 0] = p; cur[idx + 0] = p; } p += d.x;
    if (idx + 1 < M) { rowptr[idx + 1] = p; cur[idx + 1] = p; } p += d.y;
    if (idx + 2 < M) { rowptr[idx + 2] = p; cur[idx + 2] = p; } p += d.z;
    if (idx + 3 < M) { rowptr[idx + 3] = p; cur[idx + 3] = p; }
    if (b == 0 && t == 0) rowptr[M] = E;
}

__global__ __launch_bounds__(256) void fill_kernel(
    const int* __restrict__ src, const int* __restrict__ dst,
    int* __restrict__ cur, int* __restrict__ srcs, int E)
{
    const int e = blockIdx.x * 256 + threadIdx.x;
    if (e >= E) return;
    const int p = atomicAdd(&cur[dst[e]], 1);
    srcs[p] = src[e];
}

// ---------------- gathers ----------------
// d128: quarter-wave (16 lanes x 16B) covers a row; 4 neighbors in flight.
__global__ __launch_bounds__(256) void gather_add_d128(
    const short* __restrict__ feat,    // M x 128 (unpadded)
    const int* __restrict__ rowptr, const int* __restrict__ srcs,
    short* __restrict__ outb, int M)   // M x S1
{
    const int row = blockIdx.x * 4 + (threadIdx.x >> 6);
    if (row >= M) return;
    const int lane = threadIdx.x & 63;
    const int qt = lane >> 4;          // quarter 0..3
    const int o = (lane & 15) * 8;     // 8 elems (16B) per lane
    float a[8];
    #pragma unroll
    for (int k = 0; k < 8; ++k) a[k] = 0.f;
    if (qt == 0) {                     // self term once
        const uint4 u = *(const uint4*)(feat + (size_t)row * 128 + o);
        a[0] = bflo(u.x); a[1] = bfhi(u.x); a[2] = bflo(u.y); a[3] = bfhi(u.y);
        a[4] = bflo(u.z); a[5] = bfhi(u.z); a[6] = bflo(u.w); a[7] = bfhi(u.w);
    }
    const int jb = rowptr[row], je = rowptr[row + 1];
    int j = jb;
    for (; j + 8 <= je; j += 8) {      // 2 quads per iter
        uint4 v[2];
        #pragma unroll
        for (int t = 0; t < 2; ++t) {
            const int s = srcs[j + 4 * t + qt];
            v[t] = *(const uint4*)(feat + (size_t)s * 128 + o);
        }
        #pragma unroll
        for (int t = 0; t < 2; ++t) {
            a[0] += bflo(v[t].x); a[1] += bfhi(v[t].x);
            a[2] += bflo(v[t].y); a[3] += bfhi(v[t].y);
            a[4] += bflo(v[t].z); a[5] += bfhi(v[t].z);
            a[6] += bflo(v[t].w); a[7] += bfhi(v[t].w);
        }
    }
    if (j + 4 <= je) {
        const int s = srcs[j + qt];
        const uint4 v = *(const uint4*)(feat + (size_t)s * 128 + o);
        a[0] += bflo(v.x); a[1] += bfhi(v.x); a[2] += bflo(v.y); a[3] += bfhi(v.y);
        a[4] += bflo(v.z); a[5] += bfhi(v.z); a[6] += bflo(v.w); a[7] += bfhi(v.w);
        j += 4;
    }
    if (j + qt < je) {                 // 0..3 stragglers, one per quarter
        const int s = srcs[j + qt];
        const uint4 v = *(const uint4*)(feat + (size_t)s * 128 + o);
        a[0] += bflo(v.x); a[1] += bfhi(v.x); a[2] += bflo(v.y); a[3] += bfhi(v.y);
        a[4] += bflo(v.z); a[5] += bfhi(v.z); a[6] += bflo(v.w); a[7] += bfhi(v.w);
    }
    // merge quarters: qt1->qt0, qt3->qt2, then qt2->qt0
    #pragma unroll
    for (int k = 0; k < 8; ++k) {
        a[k] += __shfl_down(a[k], 16);
        a[k] += __shfl_down(a[k], 32);
    }
    if (qt == 0) {
        uint4 up;
        up.x = (unsigned int)f2bf(a[0]) | ((unsigned int)f2bf(a[1]) << 16);
        up.y = (unsigned int)f2bf(a[2]) | ((unsigned int)f2bf(a[3]) << 16);
        up.z = (unsigned int)f2bf(a[4]) | ((unsigned int)f2bf(a[5]) << 16);
        up.w = (unsigned int)f2bf(a[6]) | ((unsigned int)f2bf(a[7]) << 16);
        *(uint4*)(outb + (size_t)row * S1 + o) = up;
    }
}

// d256: half-wave covers a row at 16B/lane (8 elems), 2 neighbors in flight.
__global__ __launch_bounds__(256) void gather_add_d256(
    const short* __restrict__ feat,    // M x 256 (unpadded)
    const int* __restrict__ rowptr, const int* __restrict__ srcs,
    short* __restrict__ outb, int M)   // M x S2
{
    const int row = blockIdx.x * 4 + (threadIdx.x >> 6);
    if (row >= M) return;
    const int lane = threadIdx.x & 63;
    const int half = lane >> 5;
    const int o = (lane & 31) * 8;     // elem offset, 8 elems (16B)
    float a[8];
    #pragma unroll
    for (int k = 0; k < 8; ++k) a[k] = 0.f;
    if (half == 0) {                   // self term once
        const uint4 u = *(const uint4*)(feat + (size_t)row * 256 + o);
        a[0] = bflo(u.x); a[1] = bfhi(u.x); a[2] = bflo(u.y); a[3] = bfhi(u.y);
        a[4] = bflo(u.z); a[5] = bfhi(u.z); a[6] = bflo(u.w); a[7] = bfhi(u.w);
    }
    const int jb = rowptr[row], je = rowptr[row + 1];
    int j = jb;
    for (; j + 8 <= je; j += 8) {      // 4 pairs per iter
        uint4 v[4];
        #pragma unroll
        for (int t = 0; t < 4; ++t) {
            const int s = srcs[j + 2 * t + half];
            v[t] = *(const uint4*)(feat + (size_t)s * 256 + o);
        }
        #pragma unroll
        for (int t = 0; t < 4; ++t) {
            a[0] += bflo(v[t].x); a[1] += bfhi(v[t].x);
            a[2] += bflo(v[t].y); a[3] += bfhi(v[t].y);
            a[4] += bflo(v[t].z); a[5] += bfhi(v[t].z);
            a[6] += bflo(v[t].w); a[7] += bfhi(v[t].w);
        }
    }
    for (; j + 2 <= je; j += 2) {
        const int s = srcs[j + half];
        const uint4 v = *(const uint4*)(feat + (size_t)s * 256 + o);
        a[0] += bflo(v.x); a[1] += bfhi(v.x); a[2] += bflo(v.y); a[3] += bfhi(v.y);
        a[4] += bflo(v.z); a[5] += bfhi(v.z); a[6] += bflo(v.w); a[7] += bfhi(v.w);
    }
    if (j < je && half == 0) {
        const uint4 v = *(const uint4*)(feat + (size_t)srcs[j] * 256 + o);
        a[0] += bflo(v.x); a[1] += bfhi(v.x); a[2] += bflo(v.y); a[3] += bfhi(v.y);
        a[4] += bflo(v.z); a[5] += bfhi(v.z); a[6] += bflo(v.w); a[7] += bfhi(v.w);
    }
    #pragma unroll
    for (int k = 0; k < 8; ++k) a[k] += __shfl_down(a[k], 32);
    if (half == 0) {
        uint4 up;
        up.x = (unsigned int)f2bf(a[0]) | ((unsigned int)f2bf(a[1]) << 16);
        up.y = (unsigned int)f2bf(a[2]) | ((unsigned int)f2bf(a[3]) << 16);
        up.z = (unsigned int)f2bf(a[4]) | ((unsigned int)f2bf(a[5]) << 16);
        up.w = (unsigned int)f2bf(a[6]) | ((unsigned int)f2bf(a[7]) << 16);
        *(uint4*)(outb + (size_t)row * S2 + o) = up;
    }
}

// ---------------- layer1: h1 = relu(relu(h1in@w1+b1)@w2+b2) ----------------
__global__ __launch_bounds__(256) void layer1_fused(
    const short* __restrict__ h1in,   // M x S1 (payload 128)
    const short* __restrict__ w1t,    // 256 x S1 (payload 128)
    const float* __restrict__ b1,
    const short* __restrict__ w2t,    // 256 x S2 (payload 256)
    const float* __restrict__ b2,
    short* __restrict__ h1,           // M x 256 (unpadded)
    int M)
{
    __shared__ short sT[64 * S2];
    const int tid  = threadIdx.x;
    const int lane = tid & 63;
    const int wid  = tid >> 6;
    const int r16  = lane & 15;
    const int q    = lane >> 4;
    const int tm   = blockIdx.x * 64;
    const int wn   = wid * 64;

    f32x4 acc[4][4];
    #pragma unroll
    for (int i = 0; i < 4; ++i)
        #pragma unroll
        for (int j = 0; j < 4; ++j)
            acc[i][j] = (f32x4)0.f;

    // ---- GEMM1: t1 = relu(h1in @ w1 + b1), K = 128 ----
    const short* Abase = h1in + (size_t)tm * S1;
    #pragma unroll
    for (int k0 = 0; k0 < 128; k0 += 32) {
        bf16x8 af[4], bfr[4];
        #pragma unroll
        for (int i = 0; i < 4; ++i)
            af[i] = *(const bf16x8*)(Abase + (size_t)(i * 16 + r16) * S1 + k0 + q * 8);
        #pragma unroll
        for (int j = 0; j < 4; ++j)
            bfr[j] = *(const bf16x8*)(w1t + (size_t)(wn + j * 16 + r16) * S1 + k0 + q * 8);
        #pragma unroll
        for (int i = 0; i < 4; ++i)
            #pragma unroll
            for (int j = 0; j < 4; ++j)
                acc[i][j] = __builtin_amdgcn_mfma_f32_16x16x32_bf16(af[i], bfr[j], acc[i][j], 0, 0, 0);
    }

    // epilogue1 -> sT  (row = i*16 + q*4 + r, col = wn + j*16 + r16)
    #pragma unroll
    for (int j = 0; j < 4; ++j) {
        const int col = wn + j * 16 + r16;
        const float bj = b1[col];
        #pragma unroll
        for (int i = 0; i < 4; ++i)
            #pragma unroll
            for (int r = 0; r < 4; ++r) {
                float v = fmaxf(acc[i][j][r] + bj, 0.f);
                sT[(i * 16 + q * 4 + r) * S2 + col] = (short)f2bf(v);
            }
    }
    __syncthreads();

    // ---- GEMM2: h1 = relu(t1 @ w2 + b2), K = 256, A from LDS ----
    #pragma unroll
    for (int i = 0; i < 4; ++i)
        #pragma unroll
        for (int j = 0; j < 4; ++j)
            acc[i][j] = (f32x4)0.f;

    #pragma unroll
    for (int k0 = 0; k0 < 256; k0 += 32) {
        bf16x8 af[4], bfr[4];
        #pragma unroll
        for (int i = 0; i < 4; ++i)
            af[i] = *(const bf16x8*)(&sT[(i * 16 + r16) * S2 + k0 + q * 8]);
        #pragma unroll
        for (int j = 0; j < 4; ++j)
            bfr[j] = *(const bf16x8*)(w2t + (size_t)(wn + j * 16 + r16) * S2 + k0 + q * 8);
        #pragma unroll
        for (int i = 0; i < 4; ++i)
            #pragma unroll
            for (int j = 0; j < 4; ++j)
                acc[i][j] = __builtin_amdgcn_mfma_f32_16x16x32_bf16(af[i], bfr[j], acc[i][j], 0, 0, 0);
    }
    __syncthreads();   // all waves done reading sT

    // epilogue2 -> sT (reused as h1 tile), then coalesced store
    #pragma unroll
    for (int j = 0; j < 4; ++j) {
        const int col = wn + j * 16 + r16;
        const float bj = b2[col];
        #pragma unroll
        for (int i = 0; i < 4; ++i)
            #pragma unroll
            for (int r = 0; r < 4; ++r) {
                float v = fmaxf(acc[i][j][r] + bj, 0.f);
                sT[(i * 16 + q * 4 + r) * S2 + col] = (short)f2bf(v);
            }
    }
    __syncthreads();

    #pragma unroll
    for (int c = 0; c < 8; ++c) {
        const int idx = tid + c * 256;
        const int row = idx >> 5;
        const int ch  = idx & 31;
        const int rg  = tm + row;
        if (rg < M) {
            const uint4 v = *(const uint4*)(&sT[row * S2 + ch * 8]);
            *(uint4*)(h1 + (size_t)rg * 256 + ch * 8) = v;
        }
    }
}

// ---------------- layer2: out = log_softmax(relu(h2in@w3+b3) @ w4 + b4) ----------------
__global__ __launch_bounds__(256) void layer2_fused(
    const short* __restrict__ h2in,   // M x S2 (payload 256)
    const short* __restrict__ w3t,    // 256 x S2
    const float* __restrict__ b3,
    const float* __restrict__ w4,     // 256 x 2 fp32
    const float* __restrict__ b4,
    float* __restrict__ out,          // M x 2
    int M)
{
    __shared__ short sT[64 * S2];
    const int tid  = threadIdx.x;
    const int lane = tid & 63;
    const int wid  = tid >> 6;
    const int r16  = lane & 15;
    const int q    = lane >> 4;
    const int tm   = blockIdx.x * 64;
    const int wn   = wid * 64;

    f32x4 acc[4][4];
    #pragma unroll
    for (int i = 0; i < 4; ++i)
        #pragma unroll
        for (int j = 0; j < 4; ++j)
            acc[i][j] = (f32x4)0.f;

    const short* Abase = h2in + (size_t)tm * S2;
    #pragma unroll
    for (int k0 = 0; k0 < 256; k0 += 32) {
        bf16x8 af[4], bfr[4];
        #pragma unroll
        for (int i = 0; i < 4; ++i)
            af[i] = *(const bf16x8*)(Abase + (size_t)(i * 16 + r16) * S2 + k0 + q * 8);
        #pragma unroll
        for (int j = 0; j < 4; ++j)
            bfr[j] = *(const bf16x8*)(w3t + (size_t)(wn + j * 16 + r16) * S2 + k0 + q * 8);
        #pragma unroll
        for (int i = 0; i < 4; ++i)
            #pragma unroll
            for (int j = 0; j < 4; ++j)
                acc[i][j] = __builtin_amdgcn_mfma_f32_16x16x32_bf16(af[i], bfr[j], acc[i][j], 0, 0, 0);
    }

    // epilogue -> sT (t2 tile, bf16 + relu + bias)
    #pragma unroll
    for (int j = 0; j < 4; ++j) {
        const int col = wn + j * 16 + r16;
        const float bj = b3[col];
        #pragma unroll
        for (int i = 0; i < 4; ++i)
            #pragma unroll
            for (int r = 0; r < 4; ++r) {
                float v = fmaxf(acc[i][j][r] + bj, 0.f);
                sT[(i * 16 + q * 4 + r) * S2 + col] = (short)f2bf(v);
            }
    }
    __syncthreads();

    // head: 4 threads per row, 64 k each; shuffle-reduce width 4
    const int row = tid >> 2;
    const int qd  = tid & 3;
    const short* tp = &sT[row * S2 + qd * 64];
    const float* w4p = w4 + qd * 128;
    float s0 = 0.f, s1 = 0.f;
    #pragma unroll 8
    for (int k = 0; k < 64; ++k) {
        const float a = bf2f((unsigned short)tp[k]);
        const float2 w = *(const float2*)(w4p + 2 * k);
        s0 = fmaf(a, w.x, s0);
        s1 = fmaf(a, w.y, s1);
    }
    s0 += __shfl_down(s0, 2, 4);  s1 += __shfl_down(s1, 2, 4);
    s0 += __shfl_down(s0, 1, 4);  s1 += __shfl_down(s1, 1, 4);
    if (qd == 0) {
        const int rg = tm + row;
        if (rg < M) {
            s0 += b4[0];
            s1 += b4[1];
            const float m = fmaxf(s0, s1);
            const float l = logf(__expf(s0 - m) + __expf(s1 - m));
            float2 o;
            o.x = s0 - m - l;
            o.y = s1 - m - l;
            *(float2*)(out + (size_t)rg * 2) = o;
        }
    }
}

extern "C" void kernel_launch(void* const* d_in, const int* in_sizes, int n_in,
                              void* d_out, int out_size, void* d_ws, size_t ws_size,
                              hipStream_t stream)
{
    const float* x  = (const float*)d_in[0];
    const int*   ei = (const int*)d_in[1];
    const float* w1 = (const float*)d_in[2];
    const float* b1 = (const float*)d_in[3];
    const float* w2 = (const float*)d_in[4];
    const float* b2 = (const float*)d_in[5];
    const float* w3 = (const float*)d_in[6];
    const float* b3 = (const float*)d_in[7];
    const float* w4 = (const float*)d_in[8];
    const float* b4 = (const float*)d_in[9];

    const int DIN = 128, DH = 256;
    const int M = in_sizes[0] / DIN;   // 50000
    const int E = in_sizes[1] / 2;     // 600000
    const int* src = ei;
    const int* dst = ei + E;
    const int nB = (M + 1023) / 1024;  // <= 64

    // -------- workspace layout (deg and bsum contiguous for one memset) --------
    int* deg    = (int*)d_ws;          // M
    int* bsum   = deg + M;             // 64
    int* cur    = bsum + 64;           // M
    int* rowptr = cur + M;             // M+1
    int* srcs   = rowptr + (M + 1);    // E
    size_t off = ((size_t)(3 * M + 1 + 64 + E) * sizeof(int) + 255) & ~(size_t)255;
    short* x_bf = (short*)((char*)d_ws + off);  off += (size_t)M * DIN * 2;   // M x 128
    off = (off + 255) & ~(size_t)255;
    short* h1in = (short*)((char*)d_ws + off);  off += (size_t)M * S1 * 2;    // M x 136
    off = (off + 255) & ~(size_t)255;
    short* h1   = (short*)((char*)d_ws + off);  off += (size_t)M * DH * 2;    // M x 256
    off = (off + 255) & ~(size_t)255;
    short* h2in = (short*)((char*)d_ws + off);  off += (size_t)M * S2 * 2;    // M x 264
    off = (off + 255) & ~(size_t)255;
    short* w1t  = (short*)((char*)d_ws + off);  off += (size_t)DH * S1 * 2;   // 256 x 136
    off = (off + 255) & ~(size_t)255;
    short* w2t  = (short*)((char*)d_ws + off);  off += (size_t)DH * S2 * 2;   // 256 x 264
    off = (off + 255) & ~(size_t)255;
    short* w3t  = (short*)((char*)d_ws + off);  off += (size_t)DH * S2 * 2;   // 256 x 264

    // -------- prep: zero deg+bsum, then cvt | transpose | degree+bsum --------
    hipMemsetAsync(deg, 0, (size_t)(M + 64) * sizeof(int), stream);
    const int cB = (M * 32 + 255) / 256;     // cvt blocks
    const int dB = (E + 255) / 256;          // degree blocks
    prep_kernel<<<cB + 192 + dB, 256, 0, stream>>>(
        x, x_bf, w1, w2, w3, w1t, w2t, w3t, dst, deg, bsum, M, E, cB);

    // -------- CSR build --------
    scan_blocks2_kernel<<<nB, 256, 0, stream>>>(deg, bsum, rowptr, cur, M, E, nB);
    fill_kernel<<<dB, 256, 0, stream>>>(src, dst, cur, srcs, E);

    const int nblk = (M + 63) / 64;

    // -------- layer 1 --------
    gather_add_d128<<<(M + 3) / 4, 256, 0, stream>>>(x_bf, rowptr, srcs, h1in, M);
    layer1_fused<<<nblk, 256, 0, stream>>>(h1in, w1t, b1, w2t, b2, h1, M);

    // -------- layer 2 --------
    gather_add_d256<<<(M + 3) / 4, 256, 0, stream>>>(h1, rowptr, srcs, h2in, M);
    layer2_fused<<<nblk, 256, 0, stream>>>(h2in, w3t, b3, w4, b4, (float*)d_out, M);
}

// Round 11
// 285.107 us; speedup vs baseline: 3.8978x; 3.8978x over previous
//
#include <hip/hip_runtime.h>
#include <hip/hip_bf16.h>

// GIN 2-layer forward — R11: R10 minus the bsum atomic fold (600K atomics on
// 49 addresses serialized -> prep 860µs; R1 lesson re-learned). block_sum is
// its own contention-free kernel again. Quarter-wave d128 gather kept.
//
//   memset(deg) -> prep (cvt x | transpose w1/w2/w3 | degree atomics)
//   block_sum -> scan_blocks2 -> fill
//   h1in  = x_bf + gather(x_bf)                     [bf16, stride 136]
//   h1    = relu(relu(h1in@w1+b1)@w2+b2)            [layer1_fused, t1 in LDS only]
//   h2in  = h1 + gather(h1)                         [bf16, stride 264]
//   out   = log_softmax(relu(h2in@w3+b3)@w4+b4)     [layer2_fused, t2 in LDS only]

typedef __attribute__((ext_vector_type(8))) short bf16x8;
typedef __attribute__((ext_vector_type(4))) float f32x4;

static __device__ __forceinline__ unsigned short f2bf(float f) {
    unsigned int u = __float_as_uint(f);
    unsigned int r = (u + 0x7fffu + ((u >> 16) & 1u)) >> 16;
    return (unsigned short)r;
}
static __device__ __forceinline__ float bf2f(unsigned short s) {
    return __uint_as_float(((unsigned int)s) << 16);
}
static __device__ __forceinline__ float bflo(unsigned int u) {
    return __uint_as_float(u << 16);
}
static __device__ __forceinline__ float bfhi(unsigned int u) {
    return __uint_as_float(u & 0xffff0000u);
}

#define S1 136   // 128 + 8 pad (bf16 elems)
#define S2 264   // 256 + 8 pad

// ---------------- prep: cvt x | transpose w1/w2/w3 | degree ----------------
// deg[] must be zeroed (memsetAsync) before this kernel runs.
__global__ __launch_bounds__(256) void prep_kernel(
    const float* __restrict__ x, short* __restrict__ x_bf,
    const float* __restrict__ w1, const float* __restrict__ w2, const float* __restrict__ w3,
    short* __restrict__ w1t, short* __restrict__ w2t, short* __restrict__ w3t,
    const int* __restrict__ dst, int* __restrict__ deg,
    int M, int E, int cB)
{
    const int b = blockIdx.x;
    const int t = threadIdx.x;
    if (b < cB) {
        // cvt x -> bf16, 4 elems/thread
        const int i = b * 256 + t;
        const int n4 = M * 32;   // M*128/4
        if (i >= n4) return;
        const float4 v = *(const float4*)(x + (size_t)i * 4);
        ushort4 o;
        o.x = f2bf(v.x); o.y = f2bf(v.y); o.z = f2bf(v.z); o.w = f2bf(v.w);
        *(ushort4*)(x_bf + (size_t)i * 4) = o;
        return;
    }
    if (b < cB + 192) {
        // transpose-convert: 192 blocks: z in [0,3), 8x8 (k,n) tiles of 32
        const int tb = b - cB;
        const int z = tb >> 6;
        const int rem = tb & 63;
        const int kb = rem & 7;
        const int nb = rem >> 3;
        const float* in; short* outb; int K, ostride;
        if (z == 0)      { in = w1; outb = w1t; K = 128; ostride = S1; }
        else if (z == 1) { in = w2; outb = w2t; K = 256; ostride = S2; }
        else             { in = w3; outb = w3t; K = 256; ostride = S2; }
        const int N = 256;
        const int k0 = kb * 32;
        if (k0 >= K) return;
        const int n0 = nb * 32;
        __shared__ float tile[32][33];
        const int tx = t & 31;
        const int ty = t >> 5;   // 0..7
        #pragma unroll
        for (int i = 0; i < 4; ++i)
            tile[ty + 8 * i][tx] = in[(size_t)(k0 + ty + 8 * i) * N + n0 + tx];
        __syncthreads();
        #pragma unroll
        for (int i = 0; i < 4; ++i)
            outb[(size_t)(n0 + ty + 8 * i) * ostride + k0 + tx] = (short)f2bf(tile[tx][ty + 8 * i]);
        return;
    }
    // degree (atomics spread over M=50000 counters — fine; do NOT fold bsum
    // here: 600K atomics on 49 addresses serialized to 860µs in R10)
    const int e = (b - cB - 192) * 256 + t;
    if (e < E) atomicAdd(&deg[dst[e]], 1);
}

// ---------------- CSR build ----------------
__global__ __launch_bounds__(256) void block_sum_kernel(
    const int* __restrict__ deg, int* __restrict__ bsum, int M)
{
    const int b = blockIdx.x, t = threadIdx.x;
    const int idx = b * 1024 + t * 4;
    int s = 0;
    if (idx + 3 < M) {
        const int4 v = *(const int4*)(deg + idx);
        s = v.x + v.y + v.z + v.w;
    } else {
        #pragma unroll
        for (int i = 0; i < 4; ++i) if (idx + i < M) s += deg[idx + i];
    }
    #pragma unroll
    for (int off = 32; off > 0; off >>= 1) s += __shfl_down(s, off);
    __shared__ int ws[4];
    if ((t & 63) == 0) ws[t >> 6] = s;
    __syncthreads();
    if (t == 0) bsum[b] = ws[0] + ws[1] + ws[2] + ws[3];
}

// scan_partials fused in: every block wave-scans the <=64 bsum entries itself.
__global__ __launch_bounds__(256) void scan_blocks2_kernel(
    const int* __restrict__ deg, const int* __restrict__ bsum,
    int* __restrict__ rowptr, int* __restrict__ cur, int M, int E, int nB)
{
    const int b = blockIdx.x, t = threadIdx.x;
    __shared__ int sboff;
    if (t < 64) {
        const int v = (t < nB) ? bsum[t] : 0;
        int inc = v;
        #pragma unroll
        for (int off = 1; off < 64; off <<= 1) {
            const int u = __shfl_up(inc, off);
            if (t >= off) inc += u;
        }
        const int prev = __shfl(inc, (b == 0) ? 0 : (b - 1));
        if (t == 0) sboff = (b == 0) ? 0 : prev;
    }
    const int idx = b * 1024 + t * 4;
    int4 d = make_int4(0, 0, 0, 0);
    if (idx + 3 < M) {
        d = *(const int4*)(deg + idx);
    } else {
        if (idx + 0 < M) d.x = deg[idx + 0];
        if (idx + 1 < M) d.y = deg[idx + 1];
        if (idx + 2 < M) d.z = deg[idx + 2];
        if (idx + 3 < M) d.w = deg[idx + 3];
    }
    const int tot = d.x + d.y + d.z + d.w;
    const int lane = t & 63, wid = t >> 6;
    int inc = tot;
    #pragma unroll
    for (int off = 1; off < 64; off <<= 1) {
        const int u = __shfl_up(inc, off);
        if (lane >= off) inc += u;
    }
    __shared__ int wsum[4];
    if (lane == 63) wsum[wid] = inc;
    __syncthreads();
    int woff = 0;
    #pragma unroll
    for (int w = 0; w < 4; ++w) if (w < wid) woff += wsum[w];
    int p = sboff + woff + (inc - tot);
    if (idx + 0 < M) { rowptr[idx + 0] = p; cur[idx + 0] = p; } p += d.x;
    if (idx + 1 < M) { rowptr[idx + 1] = p; cur[idx + 1] = p; } p += d.y;
    if (idx + 2 < M) { rowptr[idx + 2] = p; cur[idx + 2] = p; } p += d.z;
    if (idx + 3 < M) { rowptr[idx + 3] = p; cur[idx + 3] = p; }
    if (b == 0 && t == 0) rowptr[M] = E;
}

__global__ __launch_bounds__(256) void fill_kernel(
    const int* __restrict__ src, const int* __restrict__ dst,
    int* __restrict__ cur, int* __restrict__ srcs, int E)
{
    const int e = blockIdx.x * 256 + threadIdx.x;
    if (e >= E) return;
    const int p = atomicAdd(&cur[dst[e]], 1);
    srcs[p] = src[e];
}

// ---------------- gathers ----------------
// d128: quarter-wave (16 lanes x 16B) covers a row; 4 neighbors in flight.
__global__ __launch_bounds__(256) void gather_add_d128(
    const short* __restrict__ feat,    // M x 128 (unpadded)
    const int* __restrict__ rowptr, const int* __restrict__ srcs,
    short* __restrict__ outb, int M)   // M x S1
{
    const int row = blockIdx.x * 4 + (threadIdx.x >> 6);
    if (row >= M) return;
    const int lane = threadIdx.x & 63;
    const int qt = lane >> 4;          // quarter 0..3
    const int o = (lane & 15) * 8;     // 8 elems (16B) per lane
    float a[8];
    #pragma unroll
    for (int k = 0; k < 8; ++k) a[k] = 0.f;
    if (qt == 0) {                     // self term once
        const uint4 u = *(const uint4*)(feat + (size_t)row * 128 + o);
        a[0] = bflo(u.x); a[1] = bfhi(u.x); a[2] = bflo(u.y); a[3] = bfhi(u.y);
        a[4] = bflo(u.z); a[5] = bfhi(u.z); a[6] = bflo(u.w); a[7] = bfhi(u.w);
    }
    const int jb = rowptr[row], je = rowptr[row + 1];
    int j = jb;
    for (; j + 8 <= je; j += 8) {      // 2 quads per iter
        uint4 v[2];
        #pragma unroll
        for (int t = 0; t < 2; ++t) {
            const int s = srcs[j + 4 * t + qt];
            v[t] = *(const uint4*)(feat + (size_t)s * 128 + o);
        }
        #pragma unroll
        for (int t = 0; t < 2; ++t) {
            a[0] += bflo(v[t].x); a[1] += bfhi(v[t].x);
            a[2] += bflo(v[t].y); a[3] += bfhi(v[t].y);
            a[4] += bflo(v[t].z); a[5] += bfhi(v[t].z);
            a[6] += bflo(v[t].w); a[7] += bfhi(v[t].w);
        }
    }
    if (j + 4 <= je) {
        const int s = srcs[j + qt];
        const uint4 v = *(const uint4*)(feat + (size_t)s * 128 + o);
        a[0] += bflo(v.x); a[1] += bfhi(v.x); a[2] += bflo(v.y); a[3] += bfhi(v.y);
        a[4] += bflo(v.z); a[5] += bfhi(v.z); a[6] += bflo(v.w); a[7] += bfhi(v.w);
        j += 4;
    }
    if (j + qt < je) {                 // 0..3 stragglers, one per quarter
        const int s = srcs[j + qt];
        const uint4 v = *(const uint4*)(feat + (size_t)s * 128 + o);
        a[0] += bflo(v.x); a[1] += bfhi(v.x); a[2] += bflo(v.y); a[3] += bfhi(v.y);
        a[4] += bflo(v.z); a[5] += bfhi(v.z); a[6] += bflo(v.w); a[7] += bfhi(v.w);
    }
    // merge quarters
    #pragma unroll
    for (int k = 0; k < 8; ++k) {
        a[k] += __shfl_down(a[k], 16);
        a[k] += __shfl_down(a[k], 32);
    }
    if (qt == 0) {
        uint4 up;
        up.x = (unsigned int)f2bf(a[0]) | ((unsigned int)f2bf(a[1]) << 16);
        up.y = (unsigned int)f2bf(a[2]) | ((unsigned int)f2bf(a[3]) << 16);
        up.z = (unsigned int)f2bf(a[4]) | ((unsigned int)f2bf(a[5]) << 16);
        up.w = (unsigned int)f2bf(a[6]) | ((unsigned int)f2bf(a[7]) << 16);
        *(uint4*)(outb + (size_t)row * S1 + o) = up;
    }
}

// d256: half-wave covers a row at 16B/lane (8 elems), 2 neighbors in flight.
__global__ __launch_bounds__(256) void gather_add_d256(
    const short* __restrict__ feat,    // M x 256 (unpadded)
    const int* __restrict__ rowptr, const int* __restrict__ srcs,
    short* __restrict__ outb, int M)   // M x S2
{
    const int row = blockIdx.x * 4 + (threadIdx.x >> 6);
    if (row >= M) return;
    const int lane = threadIdx.x & 63;
    const int half = lane >> 5;
    const int o = (lane & 31) * 8;     // elem offset, 8 elems (16B)
    float a[8];
    #pragma unroll
    for (int k = 0; k < 8; ++k) a[k] = 0.f;
    if (half == 0) {                   // self term once
        const uint4 u = *(const uint4*)(feat + (size_t)row * 256 + o);
        a[0] = bflo(u.x); a[1] = bfhi(u.x); a[2] = bflo(u.y); a[3] = bfhi(u.y);
        a[4] = bflo(u.z); a[5] = bfhi(u.z); a[6] = bflo(u.w); a[7] = bfhi(u.w);
    }
    const int jb = rowptr[row], je = rowptr[row + 1];
    int j = jb;
    for (; j + 8 <= je; j += 8) {      // 4 pairs per iter
        uint4 v[4];
        #pragma unroll
        for (int t = 0; t < 4; ++t) {
            const int s = srcs[j + 2 * t + half];
            v[t] = *(const uint4*)(feat + (size_t)s * 256 + o);
        }
        #pragma unroll
        for (int t = 0; t < 4; ++t) {
            a[0] += bflo(v[t].x); a[1] += bfhi(v[t].x);
            a[2] += bflo(v[t].y); a[3] += bfhi(v[t].y);
            a[4] += bflo(v[t].z); a[5] += bfhi(v[t].z);
            a[6] += bflo(v[t].w); a[7] += bfhi(v[t].w);
        }
    }
    for (; j + 2 <= je; j += 2) {
        const int s = srcs[j + half];
        const uint4 v = *(const uint4*)(feat + (size_t)s * 256 + o);
        a[0] += bflo(v.x); a[1] += bfhi(v.x); a[2] += bflo(v.y); a[3] += bfhi(v.y);
        a[4] += bflo(v.z); a[5] += bfhi(v.z); a[6] += bflo(v.w); a[7] += bfhi(v.w);
    }
    if (j < je && half == 0) {
        const uint4 v = *(const uint4*)(feat + (size_t)srcs[j] * 256 + o);
        a[0] += bflo(v.x); a[1] += bfhi(v.x); a[2] += bflo(v.y); a[3] += bfhi(v.y);
        a[4] += bflo(v.z); a[5] += bfhi(v.z); a[6] += bflo(v.w); a[7] += bfhi(v.w);
    }
    #pragma unroll
    for (int k = 0; k < 8; ++k) a[k] += __shfl_down(a[k], 32);
    if (half == 0) {
        uint4 up;
        up.x = (unsigned int)f2bf(a[0]) | ((unsigned int)f2bf(a[1]) << 16);
        up.y = (unsigned int)f2bf(a[2]) | ((unsigned int)f2bf(a[3]) << 16);
        up.z = (unsigned int)f2bf(a[4]) | ((unsigned int)f2bf(a[5]) << 16);
        up.w = (unsigned int)f2bf(a[6]) | ((unsigned int)f2bf(a[7]) << 16);
        *(uint4*)(outb + (size_t)row * S2 + o) = up;
    }
}

// ---------------- layer1: h1 = relu(relu(h1in@w1+b1)@w2+b2) ----------------
__global__ __launch_bounds__(256) void layer1_fused(
    const short* __restrict__ h1in,   // M x S1 (payload 128)
    const short* __restrict__ w1t,    // 256 x S1 (payload 128)
    const float* __restrict__ b1,
    const short* __restrict__ w2t,    // 256 x S2 (payload 256)
    const float* __restrict__ b2,
    short* __restrict__ h1,           // M x 256 (unpadded)
    int M)
{
    __shared__ short sT[64 * S2];
    const int tid  = threadIdx.x;
    const int lane = tid & 63;
    const int wid  = tid >> 6;
    const int r16  = lane & 15;
    const int q    = lane >> 4;
    const int tm   = blockIdx.x * 64;
    const int wn   = wid * 64;

    f32x4 acc[4][4];
    #pragma unroll
    for (int i = 0; i < 4; ++i)
        #pragma unroll
        for (int j = 0; j < 4; ++j)
            acc[i][j] = (f32x4)0.f;

    // ---- GEMM1: t1 = relu(h1in @ w1 + b1), K = 128 ----
    const short* Abase = h1in + (size_t)tm * S1;
    #pragma unroll
    for (int k0 = 0; k0 < 128; k0 += 32) {
        bf16x8 af[4], bfr[4];
        #pragma unroll
        for (int i = 0; i < 4; ++i)
            af[i] = *(const bf16x8*)(Abase + (size_t)(i * 16 + r16) * S1 + k0 + q * 8);
        #pragma unroll
        for (int j = 0; j < 4; ++j)
            bfr[j] = *(const bf16x8*)(w1t + (size_t)(wn + j * 16 + r16) * S1 + k0 + q * 8);
        #pragma unroll
        for (int i = 0; i < 4; ++i)
            #pragma unroll
            for (int j = 0; j < 4; ++j)
                acc[i][j] = __builtin_amdgcn_mfma_f32_16x16x32_bf16(af[i], bfr[j], acc[i][j], 0, 0, 0);
    }

    // epilogue1 -> sT  (row = i*16 + q*4 + r, col = wn + j*16 + r16)
    #pragma unroll
    for (int j = 0; j < 4; ++j) {
        const int col = wn + j * 16 + r16;
        const float bj = b1[col];
        #pragma unroll
        for (int i = 0; i < 4; ++i)
            #pragma unroll
            for (int r = 0; r < 4; ++r) {
                float v = fmaxf(acc[i][j][r] + bj, 0.f);
                sT[(i * 16 + q * 4 + r) * S2 + col] = (short)f2bf(v);
            }
    }
    __syncthreads();

    // ---- GEMM2: h1 = relu(t1 @ w2 + b2), K = 256, A from LDS ----
    #pragma unroll
    for (int i = 0; i < 4; ++i)
        #pragma unroll
        for (int j = 0; j < 4; ++j)
            acc[i][j] = (f32x4)0.f;

    #pragma unroll
    for (int k0 = 0; k0 < 256; k0 += 32) {
        bf16x8 af[4], bfr[4];
        #pragma unroll
        for (int i = 0; i < 4; ++i)
            af[i] = *(const bf16x8*)(&sT[(i * 16 + r16) * S2 + k0 + q * 8]);
        #pragma unroll
        for (int j = 0; j < 4; ++j)
            bfr[j] = *(const bf16x8*)(w2t + (size_t)(wn + j * 16 + r16) * S2 + k0 + q * 8);
        #pragma unroll
        for (int i = 0; i < 4; ++i)
            #pragma unroll
            for (int j = 0; j < 4; ++j)
                acc[i][j] = __builtin_amdgcn_mfma_f32_16x16x32_bf16(af[i], bfr[j], acc[i][j], 0, 0, 0);
    }
    __syncthreads();   // all waves done reading sT

    // epilogue2 -> sT (reused as h1 tile), then coalesced store
    #pragma unroll
    for (int j = 0; j < 4; ++j) {
        const int col = wn + j * 16 + r16;
        const float bj = b2[col];
        #pragma unroll
        for (int i = 0; i < 4; ++i)
            #pragma unroll
            for (int r = 0; r < 4; ++r) {
                float v = fmaxf(acc[i][j][r] + bj, 0.f);
                sT[(i * 16 + q * 4 + r) * S2 + col] = (short)f2bf(v);
            }
    }
    __syncthreads();

    #pragma unroll
    for (int c = 0; c < 8; ++c) {
        const int idx = tid + c * 256;
        const int row = idx >> 5;
        const int ch  = idx & 31;
        const int rg  = tm + row;
        if (rg < M) {
            const uint4 v = *(const uint4*)(&sT[row * S2 + ch * 8]);
            *(uint4*)(h1 + (size_t)rg * 256 + ch * 8) = v;
        }
    }
}

// ---------------- layer2: out = log_softmax(relu(h2in@w3+b3) @ w4 + b4) ----------------
__global__ __launch_bounds__(256) void layer2_fused(
    const short* __restrict__ h2in,   // M x S2 (payload 256)
    const short* __restrict__ w3t,    // 256 x S2
    const float* __restrict__ b3,
    const float* __restrict__ w4,     // 256 x 2 fp32
    const float* __restrict__ b4,
    float* __restrict__ out,          // M x 2
    int M)
{
    __shared__ short sT[64 * S2];
    const int tid  = threadIdx.x;
    const int lane = tid & 63;
    const int wid  = tid >> 6;
    const int r16  = lane & 15;
    const int q    = lane >> 4;
    const int tm   = blockIdx.x * 64;
    const int wn   = wid * 64;

    f32x4 acc[4][4];
    #pragma unroll
    for (int i = 0; i < 4; ++i)
        #pragma unroll
        for (int j = 0; j < 4; ++j)
            acc[i][j] = (f32x4)0.f;

    const short* Abase = h2in + (size_t)tm * S2;
    #pragma unroll
    for (int k0 = 0; k0 < 256; k0 += 32) {
        bf16x8 af[4], bfr[4];
        #pragma unroll
        for (int i = 0; i < 4; ++i)
            af[i] = *(const bf16x8*)(Abase + (size_t)(i * 16 + r16) * S2 + k0 + q * 8);
        #pragma unroll
        for (int j = 0; j < 4; ++j)
            bfr[j] = *(const bf16x8*)(w3t + (size_t)(wn + j * 16 + r16) * S2 + k0 + q * 8);
        #pragma unroll
        for (int i = 0; i < 4; ++i)
            #pragma unroll
            for (int j = 0; j < 4; ++j)
                acc[i][j] = __builtin_amdgcn_mfma_f32_16x16x32_bf16(af[i], bfr[j], acc[i][j], 0, 0, 0);
    }

    // epilogue -> sT (t2 tile, bf16 + relu + bias)
    #pragma unroll
    for (int j = 0; j < 4; ++j) {
        const int col = wn + j * 16 + r16;
        const float bj = b3[col];
        #pragma unroll
        for (int i = 0; i < 4; ++i)
            #pragma unroll
            for (int r = 0; r < 4; ++r) {
                float v = fmaxf(acc[i][j][r] + bj, 0.f);
                sT[(i * 16 + q * 4 + r) * S2 + col] = (short)f2bf(v);
            }
    }
    __syncthreads();

    // head: 4 threads per row, 64 k each; shuffle-reduce width 4
    const int row = tid >> 2;
    const int qd  = tid & 3;
    const short* tp = &sT[row * S2 + qd * 64];
    const float* w4p = w4 + qd * 128;
    float s0 = 0.f, s1 = 0.f;
    #pragma unroll 8
    for (int k = 0; k < 64; ++k) {
        const float a = bf2f((unsigned short)tp[k]);
        const float2 w = *(const float2*)(w4p + 2 * k);
        s0 = fmaf(a, w.x, s0);
        s1 = fmaf(a, w.y, s1);
    }
    s0 += __shfl_down(s0, 2, 4);  s1 += __shfl_down(s1, 2, 4);
    s0 += __shfl_down(s0, 1, 4);  s1 += __shfl_down(s1, 1, 4);
    if (qd == 0) {
        const int rg = tm + row;
        if (rg < M) {
            s0 += b4[0];
            s1 += b4[1];
            const float m = fmaxf(s0, s1);
            const float l = logf(__expf(s0 - m) + __expf(s1 - m));
            float2 o;
            o.x = s0 - m - l;
            o.y = s1 - m - l;
            *(float2*)(out + (size_t)rg * 2) = o;
        }
    }
}

extern "C" void kernel_launch(void* const* d_in, const int* in_sizes, int n_in,
                              void* d_out, int out_size, void* d_ws, size_t ws_size,
                              hipStream_t stream)
{
    const float* x  = (const float*)d_in[0];
    const int*   ei = (const int*)d_in[1];
    const float* w1 = (const float*)d_in[2];
    const float* b1 = (const float*)d_in[3];
    const float* w2 = (const float*)d_in[4];
    const float* b2 = (const float*)d_in[5];
    const float* w3 = (const float*)d_in[6];
    const float* b3 = (const float*)d_in[7];
    const float* w4 = (const float*)d_in[8];
    const float* b4 = (const float*)d_in[9];

    const int DIN = 128, DH = 256;
    const int M = in_sizes[0] / DIN;   // 50000
    const int E = in_sizes[1] / 2;     // 600000
    const int* src = ei;
    const int* dst = ei + E;
    const int nB = (M + 1023) / 1024;  // <= 64

    // -------- workspace layout --------
    int* deg    = (int*)d_ws;          // M
    int* bsum   = deg + M;             // 64
    int* cur    = bsum + 64;           // M
    int* rowptr = cur + M;             // M+1
    int* srcs   = rowptr + (M + 1);    // E
    size_t off = ((size_t)(3 * M + 1 + 64 + E) * sizeof(int) + 255) & ~(size_t)255;
    short* x_bf = (short*)((char*)d_ws + off);  off += (size_t)M * DIN * 2;   // M x 128
    off = (off + 255) & ~(size_t)255;
    short* h1in = (short*)((char*)d_ws + off);  off += (size_t)M * S1 * 2;    // M x 136
    off = (off + 255) & ~(size_t)255;
    short* h1   = (short*)((char*)d_ws + off);  off += (size_t)M * DH * 2;    // M x 256
    off = (off + 255) & ~(size_t)255;
    short* h2in = (short*)((char*)d_ws + off);  off += (size_t)M * S2 * 2;    // M x 264
    off = (off + 255) & ~(size_t)255;
    short* w1t  = (short*)((char*)d_ws + off);  off += (size_t)DH * S1 * 2;   // 256 x 136
    off = (off + 255) & ~(size_t)255;
    short* w2t  = (short*)((char*)d_ws + off);  off += (size_t)DH * S2 * 2;   // 256 x 264
    off = (off + 255) & ~(size_t)255;
    short* w3t  = (short*)((char*)d_ws + off);  off += (size_t)DH * S2 * 2;   // 256 x 264

    // -------- prep: zero deg, then cvt | transpose | degree --------
    hipMemsetAsync(deg, 0, (size_t)M * sizeof(int), stream);
    const int cB = (M * 32 + 255) / 256;     // cvt blocks
    const int dB = (E + 255) / 256;          // degree blocks
    prep_kernel<<<cB + 192 + dB, 256, 0, stream>>>(
        x, x_bf, w1, w2, w3, w1t, w2t, w3t, dst, deg, M, E, cB);

    // -------- CSR build --------
    block_sum_kernel<<<nB, 256, 0, stream>>>(deg, bsum, M);
    scan_blocks2_kernel<<<nB, 256, 0, stream>>>(deg, bsum, rowptr, cur, M, E, nB);
    fill_kernel<<<dB, 256, 0, stream>>>(src, dst, cur, srcs, E);

    const int nblk = (M + 63) / 64;

    // -------- layer 1 --------
    gather_add_d128<<<(M + 3) / 4, 256, 0, stream>>>(x_bf, rowptr, srcs, h1in, M);
    layer1_fused<<<nblk, 256, 0, stream>>>(h1in, w1t, b1, w2t, b2, h1, M);

    // -------- layer 2 --------
    gather_add_d256<<<(M + 3) / 4, 256, 0, stream>>>(h1, rowptr, srcs, h2in, M);
    layer2_fused<<<nblk, 256, 0, stream>>>(h2in, w3t, b3, w4, b4, (float*)d_out, M);
}

// Round 12
// 282.689 us; speedup vs baseline: 3.9312x; 1.0086x over previous
//
#include <hip/hip_runtime.h>
#include <hip/hip_bf16.h>

// GIN 2-layer forward — R12: R11 + coalesced LDS staging of the A-tile in
// both layer kernels (K-loop A-frags were 32 scattered ~200cy global loads
// per wave; now one linear 17/34KB copy + ds_read_b128).
//
//   memset(deg) -> prep (cvt x | transpose w1/w2/w3 | degree atomics)
//   block_sum -> scan_blocks2 -> fill
//   h1in  = x_bf + gather(x_bf)                     [bf16, stride 136]
//   h1    = relu(relu(h1in@w1+b1)@w2+b2)            [layer1_fused, A staged in LDS]
//   h2in  = h1 + gather(h1)                         [bf16, stride 264]
//   out   = log_softmax(relu(h2in@w3+b3)@w4+b4)     [layer2_fused, A staged in LDS]

typedef __attribute__((ext_vector_type(8))) short bf16x8;
typedef __attribute__((ext_vector_type(4))) float f32x4;

static __device__ __forceinline__ unsigned short f2bf(float f) {
    unsigned int u = __float_as_uint(f);
    unsigned int r = (u + 0x7fffu + ((u >> 16) & 1u)) >> 16;
    return (unsigned short)r;
}
static __device__ __forceinline__ float bf2f(unsigned short s) {
    return __uint_as_float(((unsigned int)s) << 16);
}
static __device__ __forceinline__ float bflo(unsigned int u) {
    return __uint_as_float(u << 16);
}
static __device__ __forceinline__ float bfhi(unsigned int u) {
    return __uint_as_float(u & 0xffff0000u);
}

#define S1 136   // 128 + 8 pad (bf16 elems); row stride 272B = 17x16B, 2-way LDS bank alias (free)
#define S2 264   // 256 + 8 pad; row stride 528B, same property

// ---------------- prep: cvt x | transpose w1/w2/w3 | degree ----------------
__global__ __launch_bounds__(256) void prep_kernel(
    const float* __restrict__ x, short* __restrict__ x_bf,
    const float* __restrict__ w1, const float* __restrict__ w2, const float* __restrict__ w3,
    short* __restrict__ w1t, short* __restrict__ w2t, short* __restrict__ w3t,
    const int* __restrict__ dst, int* __restrict__ deg,
    int M, int E, int cB)
{
    const int b = blockIdx.x;
    const int t = threadIdx.x;
    if (b < cB) {
        const int i = b * 256 + t;
        const int n4 = M * 32;   // M*128/4
        if (i >= n4) return;
        const float4 v = *(const float4*)(x + (size_t)i * 4);
        ushort4 o;
        o.x = f2bf(v.x); o.y = f2bf(v.y); o.z = f2bf(v.z); o.w = f2bf(v.w);
        *(ushort4*)(x_bf + (size_t)i * 4) = o;
        return;
    }
    if (b < cB + 192) {
        const int tb = b - cB;
        const int z = tb >> 6;
        const int rem = tb & 63;
        const int kb = rem & 7;
        const int nb = rem >> 3;
        const float* in; short* outb; int K, ostride;
        if (z == 0)      { in = w1; outb = w1t; K = 128; ostride = S1; }
        else if (z == 1) { in = w2; outb = w2t; K = 256; ostride = S2; }
        else             { in = w3; outb = w3t; K = 256; ostride = S2; }
        const int N = 256;
        const int k0 = kb * 32;
        if (k0 >= K) return;
        const int n0 = nb * 32;
        __shared__ float tile[32][33];
        const int tx = t & 31;
        const int ty = t >> 5;
        #pragma unroll
        for (int i = 0; i < 4; ++i)
            tile[ty + 8 * i][tx] = in[(size_t)(k0 + ty + 8 * i) * N + n0 + tx];
        __syncthreads();
        #pragma unroll
        for (int i = 0; i < 4; ++i)
            outb[(size_t)(n0 + ty + 8 * i) * ostride + k0 + tx] = (short)f2bf(tile[tx][ty + 8 * i]);
        return;
    }
    // degree (spread over M counters — do NOT fold bsum: R10 lesson)
    const int e = (b - cB - 192) * 256 + t;
    if (e < E) atomicAdd(&deg[dst[e]], 1);
}

// ---------------- CSR build ----------------
__global__ __launch_bounds__(256) void block_sum_kernel(
    const int* __restrict__ deg, int* __restrict__ bsum, int M)
{
    const int b = blockIdx.x, t = threadIdx.x;
    const int idx = b * 1024 + t * 4;
    int s = 0;
    if (idx + 3 < M) {
        const int4 v = *(const int4*)(deg + idx);
        s = v.x + v.y + v.z + v.w;
    } else {
        #pragma unroll
        for (int i = 0; i < 4; ++i) if (idx + i < M) s += deg[idx + i];
    }
    #pragma unroll
    for (int off = 32; off > 0; off >>= 1) s += __shfl_down(s, off);
    __shared__ int ws[4];
    if ((t & 63) == 0) ws[t >> 6] = s;
    __syncthreads();
    if (t == 0) bsum[b] = ws[0] + ws[1] + ws[2] + ws[3];
}

__global__ __launch_bounds__(256) void scan_blocks2_kernel(
    const int* __restrict__ deg, const int* __restrict__ bsum,
    int* __restrict__ rowptr, int* __restrict__ cur, int M, int E, int nB)
{
    const int b = blockIdx.x, t = threadIdx.x;
    __shared__ int sboff;
    if (t < 64) {
        const int v = (t < nB) ? bsum[t] : 0;
        int inc = v;
        #pragma unroll
        for (int off = 1; off < 64; off <<= 1) {
            const int u = __shfl_up(inc, off);
            if (t >= off) inc += u;
        }
        const int prev = __shfl(inc, (b == 0) ? 0 : (b - 1));
        if (t == 0) sboff = (b == 0) ? 0 : prev;
    }
    const int idx = b * 1024 + t * 4;
    int4 d = make_int4(0, 0, 0, 0);
    if (idx + 3 < M) {
        d = *(const int4*)(deg + idx);
    } else {
        if (idx + 0 < M) d.x = deg[idx + 0];
        if (idx + 1 < M) d.y = deg[idx + 1];
        if (idx + 2 < M) d.z = deg[idx + 2];
        if (idx + 3 < M) d.w = deg[idx + 3];
    }
    const int tot = d.x + d.y + d.z + d.w;
    const int lane = t & 63, wid = t >> 6;
    int inc = tot;
    #pragma unroll
    for (int off = 1; off < 64; off <<= 1) {
        const int u = __shfl_up(inc, off);
        if (lane >= off) inc += u;
    }
    __shared__ int wsum[4];
    if (lane == 63) wsum[wid] = inc;
    __syncthreads();
    int woff = 0;
    #pragma unroll
    for (int w = 0; w < 4; ++w) if (w < wid) woff += wsum[w];
    int p = sboff + woff + (inc - tot);
    if (idx + 0 < M) { rowptr[idx + 0] = p; cur[idx + 0] = p; } p += d.x;
    if (idx + 1 < M) { rowptr[idx + 1] = p; cur[idx + 1] = p; } p += d.y;
    if (idx + 2 < M) { rowptr[idx + 2] = p; cur[idx + 2] = p; } p += d.z;
    if (idx + 3 < M) { rowptr[idx + 3] = p; cur[idx + 3] = p; }
    if (b == 0 && t == 0) rowptr[M] = E;
}

__global__ __launch_bounds__(256) void fill_kernel(
    const int* __restrict__ src, const int* __restrict__ dst,
    int* __restrict__ cur, int* __restrict__ srcs, int E)
{
    const int e = blockIdx.x * 256 + threadIdx.x;
    if (e >= E) return;
    const int p = atomicAdd(&cur[dst[e]], 1);
    srcs[p] = src[e];
}

// ---------------- gathers ----------------
// d128: quarter-wave (16 lanes x 16B) covers a row; 4 neighbors in flight.
__global__ __launch_bounds__(256) void gather_add_d128(
    const short* __restrict__ feat,
    const int* __restrict__ rowptr, const int* __restrict__ srcs,
    short* __restrict__ outb, int M)
{
    const int row = blockIdx.x * 4 + (threadIdx.x >> 6);
    if (row >= M) return;
    const int lane = threadIdx.x & 63;
    const int qt = lane >> 4;
    const int o = (lane & 15) * 8;
    float a[8];
    #pragma unroll
    for (int k = 0; k < 8; ++k) a[k] = 0.f;
    if (qt == 0) {
        const uint4 u = *(const uint4*)(feat + (size_t)row * 128 + o);
        a[0] = bflo(u.x); a[1] = bfhi(u.x); a[2] = bflo(u.y); a[3] = bfhi(u.y);
        a[4] = bflo(u.z); a[5] = bfhi(u.z); a[6] = bflo(u.w); a[7] = bfhi(u.w);
    }
    const int jb = rowptr[row], je = rowptr[row + 1];
    int j = jb;
    for (; j + 8 <= je; j += 8) {
        uint4 v[2];
        #pragma unroll
        for (int t = 0; t < 2; ++t) {
            const int s = srcs[j + 4 * t + qt];
            v[t] = *(const uint4*)(feat + (size_t)s * 128 + o);
        }
        #pragma unroll
        for (int t = 0; t < 2; ++t) {
            a[0] += bflo(v[t].x); a[1] += bfhi(v[t].x);
            a[2] += bflo(v[t].y); a[3] += bfhi(v[t].y);
            a[4] += bflo(v[t].z); a[5] += bfhi(v[t].z);
            a[6] += bflo(v[t].w); a[7] += bfhi(v[t].w);
        }
    }
    if (j + 4 <= je) {
        const int s = srcs[j + qt];
        const uint4 v = *(const uint4*)(feat + (size_t)s * 128 + o);
        a[0] += bflo(v.x); a[1] += bfhi(v.x); a[2] += bflo(v.y); a[3] += bfhi(v.y);
        a[4] += bflo(v.z); a[5] += bfhi(v.z); a[6] += bflo(v.w); a[7] += bfhi(v.w);
        j += 4;
    }
    if (j + qt < je) {
        const int s = srcs[j + qt];
        const uint4 v = *(const uint4*)(feat + (size_t)s * 128 + o);
        a[0] += bflo(v.x); a[1] += bfhi(v.x); a[2] += bflo(v.y); a[3] += bfhi(v.y);
        a[4] += bflo(v.z); a[5] += bfhi(v.z); a[6] += bflo(v.w); a[7] += bfhi(v.w);
    }
    #pragma unroll
    for (int k = 0; k < 8; ++k) {
        a[k] += __shfl_down(a[k], 16);
        a[k] += __shfl_down(a[k], 32);
    }
    if (qt == 0) {
        uint4 up;
        up.x = (unsigned int)f2bf(a[0]) | ((unsigned int)f2bf(a[1]) << 16);
        up.y = (unsigned int)f2bf(a[2]) | ((unsigned int)f2bf(a[3]) << 16);
        up.z = (unsigned int)f2bf(a[4]) | ((unsigned int)f2bf(a[5]) << 16);
        up.w = (unsigned int)f2bf(a[6]) | ((unsigned int)f2bf(a[7]) << 16);
        *(uint4*)(outb + (size_t)row * S1 + o) = up;
    }
}

// d256: half-wave, 16B/lane, 2 neighbors in flight (fabric-floor bound).
__global__ __launch_bounds__(256) void gather_add_d256(
    const short* __restrict__ feat,
    const int* __restrict__ rowptr, const int* __restrict__ srcs,
    short* __restrict__ outb, int M)
{
    const int row = blockIdx.x * 4 + (threadIdx.x >> 6);
    if (row >= M) return;
    const int lane = threadIdx.x & 63;
    const int half = lane >> 5;
    const int o = (lane & 31) * 8;
    float a[8];
    #pragma unroll
    for (int k = 0; k < 8; ++k) a[k] = 0.f;
    if (half == 0) {
        const uint4 u = *(const uint4*)(feat + (size_t)row * 256 + o);
        a[0] = bflo(u.x); a[1] = bfhi(u.x); a[2] = bflo(u.y); a[3] = bfhi(u.y);
        a[4] = bflo(u.z); a[5] = bfhi(u.z); a[6] = bflo(u.w); a[7] = bfhi(u.w);
    }
    const int jb = rowptr[row], je = rowptr[row + 1];
    int j = jb;
    for (; j + 8 <= je; j += 8) {
        uint4 v[4];
        #pragma unroll
        for (int t = 0; t < 4; ++t) {
            const int s = srcs[j + 2 * t + half];
            v[t] = *(const uint4*)(feat + (size_t)s * 256 + o);
        }
        #pragma unroll
        for (int t = 0; t < 4; ++t) {
            a[0] += bflo(v[t].x); a[1] += bfhi(v[t].x);
            a[2] += bflo(v[t].y); a[3] += bfhi(v[t].y);
            a[4] += bflo(v[t].z); a[5] += bfhi(v[t].z);
            a[6] += bflo(v[t].w); a[7] += bfhi(v[t].w);
        }
    }
    for (; j + 2 <= je; j += 2) {
        const int s = srcs[j + half];
        const uint4 v = *(const uint4*)(feat + (size_t)s * 256 + o);
        a[0] += bflo(v.x); a[1] += bfhi(v.x); a[2] += bflo(v.y); a[3] += bfhi(v.y);
        a[4] += bflo(v.z); a[5] += bfhi(v.z); a[6] += bflo(v.w); a[7] += bfhi(v.w);
    }
    if (j < je && half == 0) {
        const uint4 v = *(const uint4*)(feat + (size_t)srcs[j] * 256 + o);
        a[0] += bflo(v.x); a[1] += bfhi(v.x); a[2] += bflo(v.y); a[3] += bfhi(v.y);
        a[4] += bflo(v.z); a[5] += bfhi(v.z); a[6] += bflo(v.w); a[7] += bfhi(v.w);
    }
    #pragma unroll
    for (int k = 0; k < 8; ++k) a[k] += __shfl_down(a[k], 32);
    if (half == 0) {
        uint4 up;
        up.x = (unsigned int)f2bf(a[0]) | ((unsigned int)f2bf(a[1]) << 16);
        up.y = (unsigned int)f2bf(a[2]) | ((unsigned int)f2bf(a[3]) << 16);
        up.z = (unsigned int)f2bf(a[4]) | ((unsigned int)f2bf(a[5]) << 16);
        up.w = (unsigned int)f2bf(a[6]) | ((unsigned int)f2bf(a[7]) << 16);
        *(uint4*)(outb + (size_t)row * S2 + o) = up;
    }
}

// ---------------- layer1: h1 = relu(relu(h1in@w1+b1)@w2+b2) ----------------
// A-tile staged coalesced into LDS (aliased with sT; +1 barrier).
__global__ __launch_bounds__(256) void layer1_fused(
    const short* __restrict__ h1in,   // M x S1 (payload 128)
    const short* __restrict__ w1t,    // 256 x S1
    const float* __restrict__ b1,
    const short* __restrict__ w2t,    // 256 x S2
    const float* __restrict__ b2,
    short* __restrict__ h1,           // M x 256 (unpadded)
    int M)
{
    __shared__ short sT[64 * S2];     // 33792 B; phase A: A-tile (64 x S1); then sT (64 x S2)
    const int tid  = threadIdx.x;
    const int lane = tid & 63;
    const int wid  = tid >> 6;
    const int r16  = lane & 15;
    const int q    = lane >> 4;
    const int tm   = blockIdx.x * 64;
    const int wn   = wid * 64;

    // ---- stage A: contiguous 64*S1 shorts (17408 B), fully coalesced ----
    {
        const short* Aslice = h1in + (size_t)tm * S1;
        #pragma unroll
        for (int c = 0; c < 5; ++c) {            // 64*S1/8 = 1088 chunks; 5*256 >= 1088
            const int idx = tid + c * 256;
            if (idx < 64 * S1 / 8) {
                const uint4 v = *(const uint4*)(Aslice + idx * 8);
                *(uint4*)(&sT[idx * 8]) = v;
            }
        }
    }
    __syncthreads();

    f32x4 acc[4][4];
    #pragma unroll
    for (int i = 0; i < 4; ++i)
        #pragma unroll
        for (int j = 0; j < 4; ++j)
            acc[i][j] = (f32x4)0.f;

    // ---- GEMM1: t1 = relu(A @ w1 + b1), K = 128, A from LDS ----
    #pragma unroll
    for (int k0 = 0; k0 < 128; k0 += 32) {
        bf16x8 af[4], bfr[4];
        #pragma unroll
        for (int i = 0; i < 4; ++i)
            af[i] = *(const bf16x8*)(&sT[(i * 16 + r16) * S1 + k0 + q * 8]);
        #pragma unroll
        for (int j = 0; j < 4; ++j)
            bfr[j] = *(const bf16x8*)(w1t + (size_t)(wn + j * 16 + r16) * S1 + k0 + q * 8);
        #pragma unroll
        for (int i = 0; i < 4; ++i)
            #pragma unroll
            for (int j = 0; j < 4; ++j)
                acc[i][j] = __builtin_amdgcn_mfma_f32_16x16x32_bf16(af[i], bfr[j], acc[i][j], 0, 0, 0);
    }
    __syncthreads();   // done reading A-tile before epilogue1 overwrites LDS

    // epilogue1 -> sT (S2 layout)
    #pragma unroll
    for (int j = 0; j < 4; ++j) {
        const int col = wn + j * 16 + r16;
        const float bj = b1[col];
        #pragma unroll
        for (int i = 0; i < 4; ++i)
            #pragma unroll
            for (int r = 0; r < 4; ++r) {
                float v = fmaxf(acc[i][j][r] + bj, 0.f);
                sT[(i * 16 + q * 4 + r) * S2 + col] = (short)f2bf(v);
            }
    }
    __syncthreads();

    // ---- GEMM2: h1 = relu(t1 @ w2 + b2), K = 256, A from LDS ----
    #pragma unroll
    for (int i = 0; i < 4; ++i)
        #pragma unroll
        for (int j = 0; j < 4; ++j)
            acc[i][j] = (f32x4)0.f;

    #pragma unroll
    for (int k0 = 0; k0 < 256; k0 += 32) {
        bf16x8 af[4], bfr[4];
        #pragma unroll
        for (int i = 0; i < 4; ++i)
            af[i] = *(const bf16x8*)(&sT[(i * 16 + r16) * S2 + k0 + q * 8]);
        #pragma unroll
        for (int j = 0; j < 4; ++j)
            bfr[j] = *(const bf16x8*)(w2t + (size_t)(wn + j * 16 + r16) * S2 + k0 + q * 8);
        #pragma unroll
        for (int i = 0; i < 4; ++i)
            #pragma unroll
            for (int j = 0; j < 4; ++j)
                acc[i][j] = __builtin_amdgcn_mfma_f32_16x16x32_bf16(af[i], bfr[j], acc[i][j], 0, 0, 0);
    }
    __syncthreads();

    // epilogue2 -> sT, then coalesced store
    #pragma unroll
    for (int j = 0; j < 4; ++j) {
        const int col = wn + j * 16 + r16;
        const float bj = b2[col];
        #pragma unroll
        for (int i = 0; i < 4; ++i)
            #pragma unroll
            for (int r = 0; r < 4; ++r) {
                float v = fmaxf(acc[i][j][r] + bj, 0.f);
                sT[(i * 16 + q * 4 + r) * S2 + col] = (short)f2bf(v);
            }
    }
    __syncthreads();

    #pragma unroll
    for (int c = 0; c < 8; ++c) {
        const int idx = tid + c * 256;
        const int row = idx >> 5;
        const int ch  = idx & 31;
        const int rg  = tm + row;
        if (rg < M) {
            const uint4 v = *(const uint4*)(&sT[row * S2 + ch * 8]);
            *(uint4*)(h1 + (size_t)rg * 256 + ch * 8) = v;
        }
    }
}

// ---------------- layer2: out = log_softmax(relu(h2in@w3+b3) @ w4 + b4) ----------------
__global__ __launch_bounds__(256) void layer2_fused(
    const short* __restrict__ h2in,   // M x S2 (payload 256)
    const short* __restrict__ w3t,    // 256 x S2
    const float* __restrict__ b3,
    const float* __restrict__ w4,     // 256 x 2 fp32
    const float* __restrict__ b4,
    float* __restrict__ out,          // M x 2
    int M)
{
    __shared__ short sT[64 * S2];     // phase A: A-tile (64 x S2); then t2 tile
    const int tid  = threadIdx.x;
    const int lane = tid & 63;
    const int wid  = tid >> 6;
    const int r16  = lane & 15;
    const int q    = lane >> 4;
    const int tm   = blockIdx.x * 64;
    const int wn   = wid * 64;

    // ---- stage A: contiguous 64*S2 shorts (33792 B), fully coalesced ----
    {
        const short* Aslice = h2in + (size_t)tm * S2;
        #pragma unroll
        for (int c = 0; c < 9; ++c) {            // 64*S2/8 = 2112 chunks; 9*256 >= 2112
            const int idx = tid + c * 256;
            if (idx < 64 * S2 / 8) {
                const uint4 v = *(const uint4*)(Aslice + idx * 8);
                *(uint4*)(&sT[idx * 8]) = v;
            }
        }
    }
    __syncthreads();

    f32x4 acc[4][4];
    #pragma unroll
    for (int i = 0; i < 4; ++i)
        #pragma unroll
        for (int j = 0; j < 4; ++j)
            acc[i][j] = (f32x4)0.f;

    // ---- GEMM3: K = 256, A from LDS ----
    #pragma unroll
    for (int k0 = 0; k0 < 256; k0 += 32) {
        bf16x8 af[4], bfr[4];
        #pragma unroll
        for (int i = 0; i < 4; ++i)
            af[i] = *(const bf16x8*)(&sT[(i * 16 + r16) * S2 + k0 + q * 8]);
        #pragma unroll
        for (int j = 0; j < 4; ++j)
            bfr[j] = *(const bf16x8*)(w3t + (size_t)(wn + j * 16 + r16) * S2 + k0 + q * 8);
        #pragma unroll
        for (int i = 0; i < 4; ++i)
            #pragma unroll
            for (int j = 0; j < 4; ++j)
                acc[i][j] = __builtin_amdgcn_mfma_f32_16x16x32_bf16(af[i], bfr[j], acc[i][j], 0, 0, 0);
    }
    __syncthreads();   // done reading A-tile before epilogue overwrites LDS

    // epilogue -> sT (t2 tile, bf16 + relu + bias)
    #pragma unroll
    for (int j = 0; j < 4; ++j) {
        const int col = wn + j * 16 + r16;
        const float bj = b3[col];
        #pragma unroll
        for (int i = 0; i < 4; ++i)
            #pragma unroll
            for (int r = 0; r < 4; ++r) {
                float v = fmaxf(acc[i][j][r] + bj, 0.f);
                sT[(i * 16 + q * 4 + r) * S2 + col] = (short)f2bf(v);
            }
    }
    __syncthreads();

    // head: 4 threads per row, 64 k each; shuffle-reduce width 4
    const int row = tid >> 2;
    const int qd  = tid & 3;
    const short* tp = &sT[row * S2 + qd * 64];
    const float* w4p = w4 + qd * 128;
    float s0 = 0.f, s1 = 0.f;
    #pragma unroll 8
    for (int k = 0; k < 64; ++k) {
        const float a = bf2f((unsigned short)tp[k]);
        const float2 w = *(const float2*)(w4p + 2 * k);
        s0 = fmaf(a, w.x, s0);
        s1 = fmaf(a, w.y, s1);
    }
    s0 += __shfl_down(s0, 2, 4);  s1 += __shfl_down(s1, 2, 4);
    s0 += __shfl_down(s0, 1, 4);  s1 += __shfl_down(s1, 1, 4);
    if (qd == 0) {
        const int rg = tm + row;
        if (rg < M) {
            s0 += b4[0];
            s1 += b4[1];
            const float m = fmaxf(s0, s1);
            const float l = logf(__expf(s0 - m) + __expf(s1 - m));
            float2 o;
            o.x = s0 - m - l;
            o.y = s1 - m - l;
            *(float2*)(out + (size_t)rg * 2) = o;
        }
    }
}

extern "C" void kernel_launch(void* const* d_in, const int* in_sizes, int n_in,
                              void* d_out, int out_size, void* d_ws, size_t ws_size,
                              hipStream_t stream)
{
    const float* x  = (const float*)d_in[0];
    const int*   ei = (const int*)d_in[1];
    const float* w1 = (const float*)d_in[2];
    const float* b1 = (const float*)d_in[3];
    const float* w2 = (const float*)d_in[4];
    const float* b2 = (const float*)d_in[5];
    const float* w3 = (const float*)d_in[6];
    const float* b3 = (const float*)d_in[7];
    const float* w4 = (const float*)d_in[8];
    const float* b4 = (const float*)d_in[9];

    const int DIN = 128, DH = 256;
    const int M = in_sizes[0] / DIN;   // 50000
    const int E = in_sizes[1] / 2;     // 600000
    const int* src = ei;
    const int* dst = ei + E;
    const int nB = (M + 1023) / 1024;  // <= 64

    // -------- workspace layout --------
    int* deg    = (int*)d_ws;          // M
    int* bsum   = deg + M;             // 64
    int* cur    = bsum + 64;           // M
    int* rowptr = cur + M;             // M+1
    int* srcs   = rowptr + (M + 1);    // E
    size_t off = ((size_t)(3 * M + 1 + 64 + E) * sizeof(int) + 255) & ~(size_t)255;
    short* x_bf = (short*)((char*)d_ws + off);  off += (size_t)M * DIN * 2;   // M x 128
    off = (off + 255) & ~(size_t)255;
    short* h1in = (short*)((char*)d_ws + off);  off += (size_t)M * S1 * 2;    // M x 136
    off = (off + 255) & ~(size_t)255;
    short* h1   = (short*)((char*)d_ws + off);  off += (size_t)M * DH * 2;    // M x 256
    off = (off + 255) & ~(size_t)255;
    short* h2in = (short*)((char*)d_ws + off);  off += (size_t)M * S2 * 2;    // M x 264
    off = (off + 255) & ~(size_t)255;
    short* w1t  = (short*)((char*)d_ws + off);  off += (size_t)DH * S1 * 2;   // 256 x 136
    off = (off + 255) & ~(size_t)255;
    short* w2t  = (short*)((char*)d_ws + off);  off += (size_t)DH * S2 * 2;   // 256 x 264
    off = (off + 255) & ~(size_t)255;
    short* w3t  = (short*)((char*)d_ws + off);  off += (size_t)DH * S2 * 2;   // 256 x 264

    // -------- prep --------
    hipMemsetAsync(deg, 0, (size_t)M * sizeof(int), stream);
    const int cB = (M * 32 + 255) / 256;
    const int dB = (E + 255) / 256;
    prep_kernel<<<cB + 192 + dB, 256, 0, stream>>>(
        x, x_bf, w1, w2, w3, w1t, w2t, w3t, dst, deg, M, E, cB);

    // -------- CSR build --------
    block_sum_kernel<<<nB, 256, 0, stream>>>(deg, bsum, M);
    scan_blocks2_kernel<<<nB, 256, 0, stream>>>(deg, bsum, rowptr, cur, M, E, nB);
    fill_kernel<<<dB, 256, 0, stream>>>(src, dst, cur, srcs, E);

    const int nblk = (M + 63) / 64;

    // -------- layer 1 --------
    gather_add_d128<<<(M + 3) / 4, 256, 0, stream>>>(x_bf, rowptr, srcs, h1in, M);
    layer1_fused<<<nblk, 256, 0, stream>>>(h1in, w1t, b1, w2t, b2, h1, M);

    // -------- layer 2 --------
    gather_add_d256<<<(M + 3) / 4, 256, 0, stream>>>(h1, rowptr, srcs, h2in, M);
    layer2_fused<<<nblk, 256, 0, stream>>>(h2in, w3t, b3, w4, b4, (float*)d_out, M);
}

// Round 13
// 273.847 us; speedup vs baseline: 4.0581x; 1.0323x over previous
//
#include <hip/hip_runtime.h>
#include <hip/hip_bf16.h>

// GIN 2-layer forward — R13: R12 + uint8 per-row-scale h1 mirror. The d256
// gather is byte-throughput-bound (4 impls pinned at 47µs / 146MB FETCH);
// h1 is post-relu >=0, so uint8 + per-row scale halves its bytes at ~0.3%
// relative error (same order as bf16 rounding).
//
//   memset(deg) -> prep (cvt x | transpose w1/w2/w3 | degree atomics)
//   block_sum -> scan_blocks2 -> fill
//   h1in  = x_bf + gather(x_bf)                        [bf16, stride 136]
//   h1q,hscale = quant(relu(relu(h1in@w1+b1)@w2+b2))   [layer1_fused, uint8 out]
//   h2in  = dequant-gather(h1q)                        [bf16, stride 264]
//   out   = log_softmax(relu(h2in@w3+b3)@w4+b4)        [layer2_fused]

typedef __attribute__((ext_vector_type(8))) short bf16x8;
typedef __attribute__((ext_vector_type(4))) float f32x4;

static __device__ __forceinline__ unsigned short f2bf(float f) {
    unsigned int u = __float_as_uint(f);
    unsigned int r = (u + 0x7fffu + ((u >> 16) & 1u)) >> 16;
    return (unsigned short)r;
}
static __device__ __forceinline__ float bf2f(unsigned short s) {
    return __uint_as_float(((unsigned int)s) << 16);
}
static __device__ __forceinline__ float bflo(unsigned int u) {
    return __uint_as_float(u << 16);
}
static __device__ __forceinline__ float bfhi(unsigned int u) {
    return __uint_as_float(u & 0xffff0000u);
}

#define S1 136   // 128 + 8 pad (bf16 elems)
#define S2 264   // 256 + 8 pad

// accumulate 8 uint8 lanes (packed in uint2) scaled by ss into a[0..7]
static __device__ __forceinline__ void acc8(float* a, uint2 v, float ss) {
    a[0] = fmaf(ss, (float)( v.x        & 0xff), a[0]);
    a[1] = fmaf(ss, (float)((v.x >> 8 ) & 0xff), a[1]);
    a[2] = fmaf(ss, (float)((v.x >> 16) & 0xff), a[2]);
    a[3] = fmaf(ss, (float)( v.x >> 24        ), a[3]);
    a[4] = fmaf(ss, (float)( v.y        & 0xff), a[4]);
    a[5] = fmaf(ss, (float)((v.y >> 8 ) & 0xff), a[5]);
    a[6] = fmaf(ss, (float)((v.y >> 16) & 0xff), a[6]);
    a[7] = fmaf(ss, (float)( v.y >> 24        ), a[7]);
}

// ---------------- prep: cvt x | transpose w1/w2/w3 | degree ----------------
__global__ __launch_bounds__(256) void prep_kernel(
    const float* __restrict__ x, short* __restrict__ x_bf,
    const float* __restrict__ w1, const float* __restrict__ w2, const float* __restrict__ w3,
    short* __restrict__ w1t, short* __restrict__ w2t, short* __restrict__ w3t,
    const int* __restrict__ dst, int* __restrict__ deg,
    int M, int E, int cB)
{
    const int b = blockIdx.x;
    const int t = threadIdx.x;
    if (b < cB) {
        const int i = b * 256 + t;
        const int n4 = M * 32;
        if (i >= n4) return;
        const float4 v = *(const float4*)(x + (size_t)i * 4);
        ushort4 o;
        o.x = f2bf(v.x); o.y = f2bf(v.y); o.z = f2bf(v.z); o.w = f2bf(v.w);
        *(ushort4*)(x_bf + (size_t)i * 4) = o;
        return;
    }
    if (b < cB + 192) {
        const int tb = b - cB;
        const int z = tb >> 6;
        const int rem = tb & 63;
        const int kb = rem & 7;
        const int nb = rem >> 3;
        const float* in; short* outb; int K, ostride;
        if (z == 0)      { in = w1; outb = w1t; K = 128; ostride = S1; }
        else if (z == 1) { in = w2; outb = w2t; K = 256; ostride = S2; }
        else             { in = w3; outb = w3t; K = 256; ostride = S2; }
        const int N = 256;
        const int k0 = kb * 32;
        if (k0 >= K) return;
        const int n0 = nb * 32;
        __shared__ float tile[32][33];
        const int tx = t & 31;
        const int ty = t >> 5;
        #pragma unroll
        for (int i = 0; i < 4; ++i)
            tile[ty + 8 * i][tx] = in[(size_t)(k0 + ty + 8 * i) * N + n0 + tx];
        __syncthreads();
        #pragma unroll
        for (int i = 0; i < 4; ++i)
            outb[(size_t)(n0 + ty + 8 * i) * ostride + k0 + tx] = (short)f2bf(tile[tx][ty + 8 * i]);
        return;
    }
    // degree (spread over M counters — never fold bsum here: R10 lesson)
    const int e = (b - cB - 192) * 256 + t;
    if (e < E) atomicAdd(&deg[dst[e]], 1);
}

// ---------------- CSR build ----------------
__global__ __launch_bounds__(256) void block_sum_kernel(
    const int* __restrict__ deg, int* __restrict__ bsum, int M)
{
    const int b = blockIdx.x, t = threadIdx.x;
    const int idx = b * 1024 + t * 4;
    int s = 0;
    if (idx + 3 < M) {
        const int4 v = *(const int4*)(deg + idx);
        s = v.x + v.y + v.z + v.w;
    } else {
        #pragma unroll
        for (int i = 0; i < 4; ++i) if (idx + i < M) s += deg[idx + i];
    }
    #pragma unroll
    for (int off = 32; off > 0; off >>= 1) s += __shfl_down(s, off);
    __shared__ int ws[4];
    if ((t & 63) == 0) ws[t >> 6] = s;
    __syncthreads();
    if (t == 0) bsum[b] = ws[0] + ws[1] + ws[2] + ws[3];
}

__global__ __launch_bounds__(256) void scan_blocks2_kernel(
    const int* __restrict__ deg, const int* __restrict__ bsum,
    int* __restrict__ rowptr, int* __restrict__ cur, int M, int E, int nB)
{
    const int b = blockIdx.x, t = threadIdx.x;
    __shared__ int sboff;
    if (t < 64) {
        const int v = (t < nB) ? bsum[t] : 0;
        int inc = v;
        #pragma unroll
        for (int off = 1; off < 64; off <<= 1) {
            const int u = __shfl_up(inc, off);
            if (t >= off) inc += u;
        }
        const int prev = __shfl(inc, (b == 0) ? 0 : (b - 1));
        if (t == 0) sboff = (b == 0) ? 0 : prev;
    }
    const int idx = b * 1024 + t * 4;
    int4 d = make_int4(0, 0, 0, 0);
    if (idx + 3 < M) {
        d = *(const int4*)(deg + idx);
    } else {
        if (idx + 0 < M) d.x = deg[idx + 0];
        if (idx + 1 < M) d.y = deg[idx + 1];
        if (idx + 2 < M) d.z = deg[idx + 2];
        if (idx + 3 < M) d.w = deg[idx + 3];
    }
    const int tot = d.x + d.y + d.z + d.w;
    const int lane = t & 63, wid = t >> 6;
    int inc = tot;
    #pragma unroll
    for (int off = 1; off < 64; off <<= 1) {
        const int u = __shfl_up(inc, off);
        if (lane >= off) inc += u;
    }
    __shared__ int wsum[4];
    if (lane == 63) wsum[wid] = inc;
    __syncthreads();
    int woff = 0;
    #pragma unroll
    for (int w = 0; w < 4; ++w) if (w < wid) woff += wsum[w];
    int p = sboff + woff + (inc - tot);
    if (idx + 0 < M) { rowptr[idx + 0] = p; cur[idx + 0] = p; } p += d.x;
    if (idx + 1 < M) { rowptr[idx + 1] = p; cur[idx + 1] = p; } p += d.y;
    if (idx + 2 < M) { rowptr[idx + 2] = p; cur[idx + 2] = p; } p += d.z;
    if (idx + 3 < M) { rowptr[idx + 3] = p; cur[idx + 3] = p; }
    if (b == 0 && t == 0) rowptr[M] = E;
}

__global__ __launch_bounds__(256) void fill_kernel(
    const int* __restrict__ src, const int* __restrict__ dst,
    int* __restrict__ cur, int* __restrict__ srcs, int E)
{
    const int e = blockIdx.x * 256 + threadIdx.x;
    if (e >= E) return;
    const int p = atomicAdd(&cur[dst[e]], 1);
    srcs[p] = src[e];
}

// ---------------- gather d128 (bf16, quarter-wave, 4 in flight) ----------------
__global__ __launch_bounds__(256) void gather_add_d128(
    const short* __restrict__ feat,
    const int* __restrict__ rowptr, const int* __restrict__ srcs,
    short* __restrict__ outb, int M)
{
    const int row = blockIdx.x * 4 + (threadIdx.x >> 6);
    if (row >= M) return;
    const int lane = threadIdx.x & 63;
    const int qt = lane >> 4;
    const int o = (lane & 15) * 8;
    float a[8];
    #pragma unroll
    for (int k = 0; k < 8; ++k) a[k] = 0.f;
    if (qt == 0) {
        const uint4 u = *(const uint4*)(feat + (size_t)row * 128 + o);
        a[0] = bflo(u.x); a[1] = bfhi(u.x); a[2] = bflo(u.y); a[3] = bfhi(u.y);
        a[4] = bflo(u.z); a[5] = bfhi(u.z); a[6] = bflo(u.w); a[7] = bfhi(u.w);
    }
    const int jb = rowptr[row], je = rowptr[row + 1];
    int j = jb;
    for (; j + 8 <= je; j += 8) {
        uint4 v[2];
        #pragma unroll
        for (int t = 0; t < 2; ++t) {
            const int s = srcs[j + 4 * t + qt];
            v[t] = *(const uint4*)(feat + (size_t)s * 128 + o);
        }
        #pragma unroll
        for (int t = 0; t < 2; ++t) {
            a[0] += bflo(v[t].x); a[1] += bfhi(v[t].x);
            a[2] += bflo(v[t].y); a[3] += bfhi(v[t].y);
            a[4] += bflo(v[t].z); a[5] += bfhi(v[t].z);
            a[6] += bflo(v[t].w); a[7] += bfhi(v[t].w);
        }
    }
    if (j + 4 <= je) {
        const int s = srcs[j + qt];
        const uint4 v = *(const uint4*)(feat + (size_t)s * 128 + o);
        a[0] += bflo(v.x); a[1] += bfhi(v.x); a[2] += bflo(v.y); a[3] += bfhi(v.y);
        a[4] += bflo(v.z); a[5] += bfhi(v.z); a[6] += bflo(v.w); a[7] += bfhi(v.w);
        j += 4;
    }
    if (j + qt < je) {
        const int s = srcs[j + qt];
        const uint4 v = *(const uint4*)(feat + (size_t)s * 128 + o);
        a[0] += bflo(v.x); a[1] += bfhi(v.x); a[2] += bflo(v.y); a[3] += bfhi(v.y);
        a[4] += bflo(v.z); a[5] += bfhi(v.z); a[6] += bflo(v.w); a[7] += bfhi(v.w);
    }
    #pragma unroll
    for (int k = 0; k < 8; ++k) {
        a[k] += __shfl_down(a[k], 16);
        a[k] += __shfl_down(a[k], 32);
    }
    if (qt == 0) {
        uint4 up;
        up.x = (unsigned int)f2bf(a[0]) | ((unsigned int)f2bf(a[1]) << 16);
        up.y = (unsigned int)f2bf(a[2]) | ((unsigned int)f2bf(a[3]) << 16);
        up.z = (unsigned int)f2bf(a[4]) | ((unsigned int)f2bf(a[5]) << 16);
        up.w = (unsigned int)f2bf(a[6]) | ((unsigned int)f2bf(a[7]) << 16);
        *(uint4*)(outb + (size_t)row * S1 + o) = up;
    }
}

// ---------------- gather d256 from uint8 mirror (half-wave, 2 in flight) ----------------
__global__ __launch_bounds__(256) void gather_add_d256q(
    const unsigned char* __restrict__ h1q,   // M x 256 uint8
    const float* __restrict__ hscale,        // M (dequant scale)
    const int* __restrict__ rowptr, const int* __restrict__ srcs,
    short* __restrict__ outb, int M)         // M x S2 bf16
{
    const int row = blockIdx.x * 4 + (threadIdx.x >> 6);
    if (row >= M) return;
    const int lane = threadIdx.x & 63;
    const int half = lane >> 5;
    const int o = (lane & 31) * 8;           // byte offset (8 elems/lane)
    float a[8];
    #pragma unroll
    for (int k = 0; k < 8; ++k) a[k] = 0.f;
    if (half == 0) {                         // self term
        const uint2 u = *(const uint2*)(h1q + (size_t)row * 256 + o);
        const float scr = hscale[row];
        acc8(a, u, scr);
    }
    const int jb = rowptr[row], je = rowptr[row + 1];
    int j = jb;
    for (; j + 8 <= je; j += 8) {            // 4 pairs per iter
        uint2 v[4]; float sc[4];
        #pragma unroll
        for (int t = 0; t < 4; ++t) {
            const int s = srcs[j + 2 * t + half];
            v[t] = *(const uint2*)(h1q + (size_t)s * 256 + o);
            sc[t] = hscale[s];
        }
        #pragma unroll
        for (int t = 0; t < 4; ++t) acc8(a, v[t], sc[t]);
    }
    for (; j + 2 <= je; j += 2) {
        const int s = srcs[j + half];
        const uint2 v = *(const uint2*)(h1q + (size_t)s * 256 + o);
        acc8(a, v, hscale[s]);
    }
    if (j < je && half == 0) {
        const int s = srcs[j];
        const uint2 v = *(const uint2*)(h1q + (size_t)s * 256 + o);
        acc8(a, v, hscale[s]);
    }
    #pragma unroll
    for (int k = 0; k < 8; ++k) a[k] += __shfl_down(a[k], 32);
    if (half == 0) {
        uint4 up;
        up.x = (unsigned int)f2bf(a[0]) | ((unsigned int)f2bf(a[1]) << 16);
        up.y = (unsigned int)f2bf(a[2]) | ((unsigned int)f2bf(a[3]) << 16);
        up.z = (unsigned int)f2bf(a[4]) | ((unsigned int)f2bf(a[5]) << 16);
        up.w = (unsigned int)f2bf(a[6]) | ((unsigned int)f2bf(a[7]) << 16);
        *(uint4*)(outb + (size_t)row * S2 + (lane & 31) * 8) = up;
    }
}

// ---------------- layer1: h1q = quant(relu(relu(h1in@w1+b1)@w2+b2)) ----------------
__global__ __launch_bounds__(256) void layer1_fused(
    const short* __restrict__ h1in,   // M x S1 (payload 128)
    const short* __restrict__ w1t,    // 256 x S1
    const float* __restrict__ b1,
    const short* __restrict__ w2t,    // 256 x S2
    const float* __restrict__ b2,
    unsigned char* __restrict__ h1q,  // M x 256 uint8
    float* __restrict__ hscale,       // M
    int M)
{
    __shared__ short sT[64 * S2];     // A-tile (64 x S1) then t1/h1 tile (64 x S2)
    __shared__ float sMax[64][4];
    __shared__ float sInv[64];
    const int tid  = threadIdx.x;
    const int lane = tid & 63;
    const int wid  = tid >> 6;
    const int r16  = lane & 15;
    const int q    = lane >> 4;
    const int tm   = blockIdx.x * 64;
    const int wn   = wid * 64;

    // ---- stage A: contiguous 64*S1 shorts, coalesced ----
    {
        const short* Aslice = h1in + (size_t)tm * S1;
        #pragma unroll
        for (int c = 0; c < 5; ++c) {
            const int idx = tid + c * 256;
            if (idx < 64 * S1 / 8) {
                const uint4 v = *(const uint4*)(Aslice + idx * 8);
                *(uint4*)(&sT[idx * 8]) = v;
            }
        }
    }
    __syncthreads();

    f32x4 acc[4][4];
    #pragma unroll
    for (int i = 0; i < 4; ++i)
        #pragma unroll
        for (int j = 0; j < 4; ++j)
            acc[i][j] = (f32x4)0.f;

    // ---- GEMM1: K=128, A from LDS ----
    #pragma unroll
    for (int k0 = 0; k0 < 128; k0 += 32) {
        bf16x8 af[4], bfr[4];
        #pragma unroll
        for (int i = 0; i < 4; ++i)
            af[i] = *(const bf16x8*)(&sT[(i * 16 + r16) * S1 + k0 + q * 8]);
        #pragma unroll
        for (int j = 0; j < 4; ++j)
            bfr[j] = *(const bf16x8*)(w1t + (size_t)(wn + j * 16 + r16) * S1 + k0 + q * 8);
        #pragma unroll
        for (int i = 0; i < 4; ++i)
            #pragma unroll
            for (int j = 0; j < 4; ++j)
                acc[i][j] = __builtin_amdgcn_mfma_f32_16x16x32_bf16(af[i], bfr[j], acc[i][j], 0, 0, 0);
    }
    __syncthreads();

    // epilogue1 -> sT (S2 layout)
    #pragma unroll
    for (int j = 0; j < 4; ++j) {
        const int col = wn + j * 16 + r16;
        const float bj = b1[col];
        #pragma unroll
        for (int i = 0; i < 4; ++i)
            #pragma unroll
            for (int r = 0; r < 4; ++r) {
                float v = fmaxf(acc[i][j][r] + bj, 0.f);
                sT[(i * 16 + q * 4 + r) * S2 + col] = (short)f2bf(v);
            }
    }
    __syncthreads();

    // ---- GEMM2: K=256, A from sT ----
    #pragma unroll
    for (int i = 0; i < 4; ++i)
        #pragma unroll
        for (int j = 0; j < 4; ++j)
            acc[i][j] = (f32x4)0.f;

    #pragma unroll
    for (int k0 = 0; k0 < 256; k0 += 32) {
        bf16x8 af[4], bfr[4];
        #pragma unroll
        for (int i = 0; i < 4; ++i)
            af[i] = *(const bf16x8*)(&sT[(i * 16 + r16) * S2 + k0 + q * 8]);
        #pragma unroll
        for (int j = 0; j < 4; ++j)
            bfr[j] = *(const bf16x8*)(w2t + (size_t)(wn + j * 16 + r16) * S2 + k0 + q * 8);
        #pragma unroll
        for (int i = 0; i < 4; ++i)
            #pragma unroll
            for (int j = 0; j < 4; ++j)
                acc[i][j] = __builtin_amdgcn_mfma_f32_16x16x32_bf16(af[i], bfr[j], acc[i][j], 0, 0, 0);
    }
    __syncthreads();

    // epilogue2 -> sT + per-row max (this wave's 64-col slice)
    {
        float bj4[4];
        #pragma unroll
        for (int j = 0; j < 4; ++j) bj4[j] = b2[wn + j * 16 + r16];
        #pragma unroll
        for (int i = 0; i < 4; ++i) {
            #pragma unroll
            for (int r = 0; r < 4; ++r) {
                float m = 0.f;
                #pragma unroll
                for (int j = 0; j < 4; ++j) {
                    float v = fmaxf(acc[i][j][r] + bj4[j], 0.f);
                    sT[(i * 16 + q * 4 + r) * S2 + wn + j * 16 + r16] = (short)f2bf(v);
                    m = fmaxf(m, v);
                }
                // reduce over the 16 lanes of this quarter (r16 dimension)
                #pragma unroll
                for (int off = 1; off < 16; off <<= 1)
                    m = fmaxf(m, __shfl_xor(m, off));
                if (r16 == 0) sMax[i * 16 + q * 4 + r][wid] = m;
            }
        }
    }
    __syncthreads();

    if (tid < 64) {
        const float m = fmaxf(fmaxf(sMax[tid][0], sMax[tid][1]),
                              fmaxf(sMax[tid][2], sMax[tid][3]));
        sInv[tid] = (m > 0.f) ? 255.f / m : 0.f;
        const int rg = tm + tid;
        if (rg < M) hscale[rg] = m * (1.f / 255.f);
    }
    __syncthreads();

    // quantized store: 64 rows x 256 uint8; 8B per thread-iter, coalesced
    #pragma unroll
    for (int c = 0; c < 8; ++c) {
        const int idx = tid + c * 256;
        const int row = idx >> 5;
        const int ch  = idx & 31;
        const int rg  = tm + row;
        if (rg < M) {
            const uint4 v = *(const uint4*)(&sT[row * S2 + ch * 8]);
            const float inv = sInv[row];
            unsigned int q0 = min(255u, (unsigned int)(bflo(v.x) * inv + 0.5f));
            unsigned int q1 = min(255u, (unsigned int)(bfhi(v.x) * inv + 0.5f));
            unsigned int q2 = min(255u, (unsigned int)(bflo(v.y) * inv + 0.5f));
            unsigned int q3 = min(255u, (unsigned int)(bfhi(v.y) * inv + 0.5f));
            unsigned int q4 = min(255u, (unsigned int)(bflo(v.z) * inv + 0.5f));
            unsigned int q5 = min(255u, (unsigned int)(bfhi(v.z) * inv + 0.5f));
            unsigned int q6 = min(255u, (unsigned int)(bflo(v.w) * inv + 0.5f));
            unsigned int q7 = min(255u, (unsigned int)(bfhi(v.w) * inv + 0.5f));
            uint2 o8;
            o8.x = q0 | (q1 << 8) | (q2 << 16) | (q3 << 24);
            o8.y = q4 | (q5 << 8) | (q6 << 16) | (q7 << 24);
            *(uint2*)(h1q + (size_t)rg * 256 + ch * 8) = o8;
        }
    }
}

// ---------------- layer2: out = log_softmax(relu(h2in@w3+b3) @ w4 + b4) ----------------
__global__ __launch_bounds__(256) void layer2_fused(
    const short* __restrict__ h2in,   // M x S2 (payload 256)
    const short* __restrict__ w3t,    // 256 x S2
    const float* __restrict__ b3,
    const float* __restrict__ w4,     // 256 x 2 fp32
    const float* __restrict__ b4,
    float* __restrict__ out,          // M x 2
    int M)
{
    __shared__ short sT[64 * S2];
    const int tid  = threadIdx.x;
    const int lane = tid & 63;
    const int wid  = tid >> 6;
    const int r16  = lane & 15;
    const int q    = lane >> 4;
    const int tm   = blockIdx.x * 64;
    const int wn   = wid * 64;

    // ---- stage A: contiguous 64*S2 shorts, coalesced ----
    {
        const short* Aslice = h2in + (size_t)tm * S2;
        #pragma unroll
        for (int c = 0; c < 9; ++c) {
            const int idx = tid + c * 256;
            if (idx < 64 * S2 / 8) {
                const uint4 v = *(const uint4*)(Aslice + idx * 8);
                *(uint4*)(&sT[idx * 8]) = v;
            }
        }
    }
    __syncthreads();

    f32x4 acc[4][4];
    #pragma unroll
    for (int i = 0; i < 4; ++i)
        #pragma unroll
        for (int j = 0; j < 4; ++j)
            acc[i][j] = (f32x4)0.f;

    #pragma unroll
    for (int k0 = 0; k0 < 256; k0 += 32) {
        bf16x8 af[4], bfr[4];
        #pragma unroll
        for (int i = 0; i < 4; ++i)
            af[i] = *(const bf16x8*)(&sT[(i * 16 + r16) * S2 + k0 + q * 8]);
        #pragma unroll
        for (int j = 0; j < 4; ++j)
            bfr[j] = *(const bf16x8*)(w3t + (size_t)(wn + j * 16 + r16) * S2 + k0 + q * 8);
        #pragma unroll
        for (int i = 0; i < 4; ++i)
            #pragma unroll
            for (int j = 0; j < 4; ++j)
                acc[i][j] = __builtin_amdgcn_mfma_f32_16x16x32_bf16(af[i], bfr[j], acc[i][j], 0, 0, 0);
    }
    __syncthreads();

    #pragma unroll
    for (int j = 0; j < 4; ++j) {
        const int col = wn + j * 16 + r16;
        const float bj = b3[col];
        #pragma unroll
        for (int i = 0; i < 4; ++i)
            #pragma unroll
            for (int r = 0; r < 4; ++r) {
                float v = fmaxf(acc[i][j][r] + bj, 0.f);
                sT[(i * 16 + q * 4 + r) * S2 + col] = (short)f2bf(v);
            }
    }
    __syncthreads();

    const int row = tid >> 2;
    const int qd  = tid & 3;
    const short* tp = &sT[row * S2 + qd * 64];
    const float* w4p = w4 + qd * 128;
    float s0 = 0.f, s1 = 0.f;
    #pragma unroll 8
    for (int k = 0; k < 64; ++k) {
        const float a = bf2f((unsigned short)tp[k]);
        const float2 w = *(const float2*)(w4p + 2 * k);
        s0 = fmaf(a, w.x, s0);
        s1 = fmaf(a, w.y, s1);
    }
    s0 += __shfl_down(s0, 2, 4);  s1 += __shfl_down(s1, 2, 4);
    s0 += __shfl_down(s0, 1, 4);  s1 += __shfl_down(s1, 1, 4);
    if (qd == 0) {
        const int rg = tm + row;
        if (rg < M) {
            s0 += b4[0];
            s1 += b4[1];
            const float m = fmaxf(s0, s1);
            const float l = logf(__expf(s0 - m) + __expf(s1 - m));
            float2 o;
            o.x = s0 - m - l;
            o.y = s1 - m - l;
            *(float2*)(out + (size_t)rg * 2) = o;
        }
    }
}

extern "C" void kernel_launch(void* const* d_in, const int* in_sizes, int n_in,
                              void* d_out, int out_size, void* d_ws, size_t ws_size,
                              hipStream_t stream)
{
    const float* x  = (const float*)d_in[0];
    const int*   ei = (const int*)d_in[1];
    const float* w1 = (const float*)d_in[2];
    const float* b1 = (const float*)d_in[3];
    const float* w2 = (const float*)d_in[4];
    const float* b2 = (const float*)d_in[5];
    const float* w3 = (const float*)d_in[6];
    const float* b3 = (const float*)d_in[7];
    const float* w4 = (const float*)d_in[8];
    const float* b4 = (const float*)d_in[9];

    const int DIN = 128, DH = 256;
    const int M = in_sizes[0] / DIN;   // 50000
    const int E = in_sizes[1] / 2;     // 600000
    const int* src = ei;
    const int* dst = ei + E;
    const int nB = (M + 1023) / 1024;  // <= 64

    // -------- workspace layout --------
    int* deg    = (int*)d_ws;          // M
    int* bsum   = deg + M;             // 64
    int* cur    = bsum + 64;           // M
    int* rowptr = cur + M;             // M+1
    int* srcs   = rowptr + (M + 1);    // E
    size_t off = ((size_t)(3 * M + 1 + 64 + E) * sizeof(int) + 255) & ~(size_t)255;
    short* x_bf = (short*)((char*)d_ws + off);  off += (size_t)M * DIN * 2;   // M x 128 bf16
    off = (off + 255) & ~(size_t)255;
    short* h1in = (short*)((char*)d_ws + off);  off += (size_t)M * S1 * 2;    // M x 136 bf16
    off = (off + 255) & ~(size_t)255;
    unsigned char* h1q = (unsigned char*)((char*)d_ws + off);  off += (size_t)M * 256; // M x 256 u8
    off = (off + 255) & ~(size_t)255;
    float* hscale = (float*)((char*)d_ws + off);  off += (size_t)M * 4;       // M fp32
    off = (off + 255) & ~(size_t)255;
    short* h2in = (short*)((char*)d_ws + off);  off += (size_t)M * S2 * 2;    // M x 264 bf16
    off = (off + 255) & ~(size_t)255;
    short* w1t  = (short*)((char*)d_ws + off);  off += (size_t)DH * S1 * 2;
    off = (off + 255) & ~(size_t)255;
    short* w2t  = (short*)((char*)d_ws + off);  off += (size_t)DH * S2 * 2;
    off = (off + 255) & ~(size_t)255;
    short* w3t  = (short*)((char*)d_ws + off);  off += (size_t)DH * S2 * 2;

    // -------- prep --------
    hipMemsetAsync(deg, 0, (size_t)M * sizeof(int), stream);
    const int cB = (M * 32 + 255) / 256;
    const int dB = (E + 255) / 256;
    prep_kernel<<<cB + 192 + dB, 256, 0, stream>>>(
        x, x_bf, w1, w2, w3, w1t, w2t, w3t, dst, deg, M, E, cB);

    // -------- CSR build --------
    block_sum_kernel<<<nB, 256, 0, stream>>>(deg, bsum, M);
    scan_blocks2_kernel<<<nB, 256, 0, stream>>>(deg, bsum, rowptr, cur, M, E, nB);
    fill_kernel<<<dB, 256, 0, stream>>>(src, dst, cur, srcs, E);

    const int nblk = (M + 63) / 64;

    // -------- layer 1 --------
    gather_add_d128<<<(M + 3) / 4, 256, 0, stream>>>(x_bf, rowptr, srcs, h1in, M);
    layer1_fused<<<nblk, 256, 0, stream>>>(h1in, w1t, b1, w2t, b2, h1q, hscale, M);

    // -------- layer 2 --------
    gather_add_d256q<<<(M + 3) / 4, 256, 0, stream>>>(h1q, hscale, rowptr, srcs, h2in, M);
    layer2_fused<<<nblk, 256, 0, stream>>>(h2in, w3t, b3, w4, b4, (float*)d_out, M);
}

// Round 14
// 271.472 us; speedup vs baseline: 4.0936x; 1.0087x over previous
//
#include <hip/hip_runtime.h>
#include <hip/hip_bf16.h>

// GIN 2-layer forward — R14: R13 + int8 (offset-encoded u8) x mirror for the
// layer-1 gather. Same byte-halving lever that took the d256 gather from
// 47->~33µs; x ~ N(0,1) quantizes at 0.4% relative error with per-row
// absmax scale. x_bf is dead (gather was its only consumer).
//
//   memset(deg) -> prep (quant x -> u8 + scale | transpose w | degree atomics)
//   block_sum -> scan_blocks2 -> fill
//   h1in  = dequant-gather(x_q)                        [bf16, stride 136]
//   h1q,hscale = quant(relu(relu(h1in@w1+b1)@w2+b2))   [layer1_fused, uint8 out]
//   h2in  = dequant-gather(h1q)                        [bf16, stride 264]
//   out   = log_softmax(relu(h2in@w3+b3)@w4+b4)        [layer2_fused]

typedef __attribute__((ext_vector_type(8))) short bf16x8;
typedef __attribute__((ext_vector_type(4))) float f32x4;

static __device__ __forceinline__ unsigned short f2bf(float f) {
    unsigned int u = __float_as_uint(f);
    unsigned int r = (u + 0x7fffu + ((u >> 16) & 1u)) >> 16;
    return (unsigned short)r;
}
static __device__ __forceinline__ float bf2f(unsigned short s) {
    return __uint_as_float(((unsigned int)s) << 16);
}
static __device__ __forceinline__ float bflo(unsigned int u) {
    return __uint_as_float(u << 16);
}
static __device__ __forceinline__ float bfhi(unsigned int u) {
    return __uint_as_float(u & 0xffff0000u);
}

#define S1 136   // 128 + 8 pad (bf16 elems)
#define S2 264   // 256 + 8 pad

// accumulate 8 uint8 lanes (packed uint2) scaled by ss into a[0..7]
// (ubyte extracts fold to v_cvt_f32_ubyte0..3)
static __device__ __forceinline__ void acc8(float* a, uint2 v, float ss) {
    a[0] = fmaf(ss, (float)( v.x        & 0xff), a[0]);
    a[1] = fmaf(ss, (float)((v.x >> 8 ) & 0xff), a[1]);
    a[2] = fmaf(ss, (float)((v.x >> 16) & 0xff), a[2]);
    a[3] = fmaf(ss, (float)( v.x >> 24        ), a[3]);
    a[4] = fmaf(ss, (float)( v.y        & 0xff), a[4]);
    a[5] = fmaf(ss, (float)((v.y >> 8 ) & 0xff), a[5]);
    a[6] = fmaf(ss, (float)((v.y >> 16) & 0xff), a[6]);
    a[7] = fmaf(ss, (float)( v.y >> 24        ), a[7]);
}

// ---------------- prep: quant x | transpose w1/w2/w3 | degree ----------------
__global__ __launch_bounds__(256) void prep_kernel(
    const float* __restrict__ x,
    unsigned char* __restrict__ x_q, float* __restrict__ xscale,
    const float* __restrict__ w1, const float* __restrict__ w2, const float* __restrict__ w3,
    short* __restrict__ w1t, short* __restrict__ w2t, short* __restrict__ w3t,
    const int* __restrict__ dst, int* __restrict__ deg,
    int M, int E, int cB)
{
    const int b = blockIdx.x;
    const int t = threadIdx.x;
    if (b < cB) {
        // quantize x -> offset u8, per-row (128 elems = 32 threads) absmax scale
        const int i = b * 256 + t;       // global 4-elem group
        const int n4 = M * 32;           // M*128/4
        if (i >= n4) return;
        const float4 v = *(const float4*)(x + (size_t)i * 4);
        float mx = fmaxf(fmaxf(fabsf(v.x), fabsf(v.y)), fmaxf(fabsf(v.z), fabsf(v.w)));
        #pragma unroll
        for (int o2 = 1; o2 < 32; o2 <<= 1)
            mx = fmaxf(mx, __shfl_xor(mx, o2));      // butterfly within 32-lane row group
        const float inv = (mx > 0.f) ? 127.f / mx : 0.f;
        uchar4 o;
        o.x = (unsigned char)(int)(v.x * inv + 128.5f);
        o.y = (unsigned char)(int)(v.y * inv + 128.5f);
        o.z = (unsigned char)(int)(v.z * inv + 128.5f);
        o.w = (unsigned char)(int)(v.w * inv + 128.5f);
        const int row = i >> 5;
        *(uchar4*)(x_q + (size_t)row * 128 + (i & 31) * 4) = o;
        if ((t & 31) == 0) xscale[row] = (mx > 0.f) ? mx * (1.f / 127.f) : 0.f;
        return;
    }
    if (b < cB + 192) {
        const int tb = b - cB;
        const int z = tb >> 6;
        const int rem = tb & 63;
        const int kb = rem & 7;
        const int nb = rem >> 3;
        const float* in; short* outb; int K, ostride;
        if (z == 0)      { in = w1; outb = w1t; K = 128; ostride = S1; }
        else if (z == 1) { in = w2; outb = w2t; K = 256; ostride = S2; }
        else             { in = w3; outb = w3t; K = 256; ostride = S2; }
        const int N = 256;
        const int k0 = kb * 32;
        if (k0 >= K) return;
        const int n0 = nb * 32;
        __shared__ float tile[32][33];
        const int tx = t & 31;
        const int ty = t >> 5;
        #pragma unroll
        for (int i = 0; i < 4; ++i)
            tile[ty + 8 * i][tx] = in[(size_t)(k0 + ty + 8 * i) * N + n0 + tx];
        __syncthreads();
        #pragma unroll
        for (int i = 0; i < 4; ++i)
            outb[(size_t)(n0 + ty + 8 * i) * ostride + k0 + tx] = (short)f2bf(tile[tx][ty + 8 * i]);
        return;
    }
    // degree (spread over M counters — never fold bsum here: R10 lesson)
    const int e = (b - cB - 192) * 256 + t;
    if (e < E) atomicAdd(&deg[dst[e]], 1);
}

// ---------------- CSR build ----------------
__global__ __launch_bounds__(256) void block_sum_kernel(
    const int* __restrict__ deg, int* __restrict__ bsum, int M)
{
    const int b = blockIdx.x, t = threadIdx.x;
    const int idx = b * 1024 + t * 4;
    int s = 0;
    if (idx + 3 < M) {
        const int4 v = *(const int4*)(deg + idx);
        s = v.x + v.y + v.z + v.w;
    } else {
        #pragma unroll
        for (int i = 0; i < 4; ++i) if (idx + i < M) s += deg[idx + i];
    }
    #pragma unroll
    for (int off = 32; off > 0; off >>= 1) s += __shfl_down(s, off);
    __shared__ int ws[4];
    if ((t & 63) == 0) ws[t >> 6] = s;
    __syncthreads();
    if (t == 0) bsum[b] = ws[0] + ws[1] + ws[2] + ws[3];
}

__global__ __launch_bounds__(256) void scan_blocks2_kernel(
    const int* __restrict__ deg, const int* __restrict__ bsum,
    int* __restrict__ rowptr, int* __restrict__ cur, int M, int E, int nB)
{
    const int b = blockIdx.x, t = threadIdx.x;
    __shared__ int sboff;
    if (t < 64) {
        const int v = (t < nB) ? bsum[t] : 0;
        int inc = v;
        #pragma unroll
        for (int off = 1; off < 64; off <<= 1) {
            const int u = __shfl_up(inc, off);
            if (t >= off) inc += u;
        }
        const int prev = __shfl(inc, (b == 0) ? 0 : (b - 1));
        if (t == 0) sboff = (b == 0) ? 0 : prev;
    }
    const int idx = b * 1024 + t * 4;
    int4 d = make_int4(0, 0, 0, 0);
    if (idx + 3 < M) {
        d = *(const int4*)(deg + idx);
    } else {
        if (idx + 0 < M) d.x = deg[idx + 0];
        if (idx + 1 < M) d.y = deg[idx + 1];
        if (idx + 2 < M) d.z = deg[idx + 2];
        if (idx + 3 < M) d.w = deg[idx + 3];
    }
    const int tot = d.x + d.y + d.z + d.w;
    const int lane = t & 63, wid = t >> 6;
    int inc = tot;
    #pragma unroll
    for (int off = 1; off < 64; off <<= 1) {
        const int u = __shfl_up(inc, off);
        if (lane >= off) inc += u;
    }
    __shared__ int wsum[4];
    if (lane == 63) wsum[wid] = inc;
    __syncthreads();
    int woff = 0;
    #pragma unroll
    for (int w = 0; w < 4; ++w) if (w < wid) woff += wsum[w];
    int p = sboff + woff + (inc - tot);
    if (idx + 0 < M) { rowptr[idx + 0] = p; cur[idx + 0] = p; } p += d.x;
    if (idx + 1 < M) { rowptr[idx + 1] = p; cur[idx + 1] = p; } p += d.y;
    if (idx + 2 < M) { rowptr[idx + 2] = p; cur[idx + 2] = p; } p += d.z;
    if (idx + 3 < M) { rowptr[idx + 3] = p; cur[idx + 3] = p; }
    if (b == 0 && t == 0) rowptr[M] = E;
}

__global__ __launch_bounds__(256) void fill_kernel(
    const int* __restrict__ src, const int* __restrict__ dst,
    int* __restrict__ cur, int* __restrict__ srcs, int E)
{
    const int e = blockIdx.x * 256 + threadIdx.x;
    if (e >= E) return;
    const int p = atomicAdd(&cur[dst[e]], 1);
    srcs[p] = src[e];
}

// ---------------- gather d128 from u8 mirror (quarter-wave, 4 in flight) ----------------
__global__ __launch_bounds__(256) void gather_add_d128q(
    const unsigned char* __restrict__ x_q,   // M x 128 u8 (offset-encoded)
    const float* __restrict__ xscale,        // M
    const int* __restrict__ rowptr, const int* __restrict__ srcs,
    short* __restrict__ outb, int M)         // M x S1 bf16
{
    const int row = blockIdx.x * 4 + (threadIdx.x >> 6);
    if (row >= M) return;
    const int lane = threadIdx.x & 63;
    const int qt = lane >> 4;          // quarter 0..3
    const int o = (lane & 15) * 8;     // byte/elem offset (8 elems per lane)
    float a[8];
    #pragma unroll
    for (int k = 0; k < 8; ++k) a[k] = 0.f;
    float ssum = 0.f;
    if (qt == 0) {                     // self term
        const uint2 u = *(const uint2*)(x_q + (size_t)row * 128 + o);
        const float sc = xscale[row];
        acc8(a, u, sc);
        ssum += sc;
    }
    const int jb = rowptr[row], je = rowptr[row + 1];
    int j = jb;
    for (; j + 8 <= je; j += 8) {      // 2 per quarter
        uint2 v[2]; float sc[2];
        #pragma unroll
        for (int t = 0; t < 2; ++t) {
            const int s = srcs[j + 4 * t + qt];
            v[t] = *(const uint2*)(x_q + (size_t)s * 128 + o);
            sc[t] = xscale[s];
        }
        #pragma unroll
        for (int t = 0; t < 2; ++t) { acc8(a, v[t], sc[t]); ssum += sc[t]; }
    }
    if (j + 4 <= je) {
        const int s = srcs[j + qt];
        const uint2 v = *(const uint2*)(x_q + (size_t)s * 128 + o);
        const float sc = xscale[s];
        acc8(a, v, sc);
        ssum += sc;
        j += 4;
    }
    if (j + qt < je) {                 // 0..3 stragglers, one per quarter
        const int s = srcs[j + qt];
        const uint2 v = *(const uint2*)(x_q + (size_t)s * 128 + o);
        const float sc = xscale[s];
        acc8(a, v, sc);
        ssum += sc;
    }
    // offset correction: dequant = sc*u - 128*sc
    #pragma unroll
    for (int k = 0; k < 8; ++k) a[k] = fmaf(-128.f, ssum, a[k]);
    // merge quarters
    #pragma unroll
    for (int k = 0; k < 8; ++k) {
        a[k] += __shfl_down(a[k], 16);
        a[k] += __shfl_down(a[k], 32);
    }
    if (qt == 0) {
        uint4 up;
        up.x = (unsigned int)f2bf(a[0]) | ((unsigned int)f2bf(a[1]) << 16);
        up.y = (unsigned int)f2bf(a[2]) | ((unsigned int)f2bf(a[3]) << 16);
        up.z = (unsigned int)f2bf(a[4]) | ((unsigned int)f2bf(a[5]) << 16);
        up.w = (unsigned int)f2bf(a[6]) | ((unsigned int)f2bf(a[7]) << 16);
        *(uint4*)(outb + (size_t)row * S1 + o) = up;
    }
}

// ---------------- gather d256 from uint8 mirror (half-wave, 2 in flight) ----------------
__global__ __launch_bounds__(256) void gather_add_d256q(
    const unsigned char* __restrict__ h1q,   // M x 256 uint8 (>=0, no offset)
    const float* __restrict__ hscale,        // M
    const int* __restrict__ rowptr, const int* __restrict__ srcs,
    short* __restrict__ outb, int M)         // M x S2 bf16
{
    const int row = blockIdx.x * 4 + (threadIdx.x >> 6);
    if (row >= M) return;
    const int lane = threadIdx.x & 63;
    const int half = lane >> 5;
    const int o = (lane & 31) * 8;
    float a[8];
    #pragma unroll
    for (int k = 0; k < 8; ++k) a[k] = 0.f;
    if (half == 0) {
        const uint2 u = *(const uint2*)(h1q + (size_t)row * 256 + o);
        acc8(a, u, hscale[row]);
    }
    const int jb = rowptr[row], je = rowptr[row + 1];
    int j = jb;
    for (; j + 8 <= je; j += 8) {
        uint2 v[4]; float sc[4];
        #pragma unroll
        for (int t = 0; t < 4; ++t) {
            const int s = srcs[j + 2 * t + half];
            v[t] = *(const uint2*)(h1q + (size_t)s * 256 + o);
            sc[t] = hscale[s];
        }
        #pragma unroll
        for (int t = 0; t < 4; ++t) acc8(a, v[t], sc[t]);
    }
    for (; j + 2 <= je; j += 2) {
        const int s = srcs[j + half];
        const uint2 v = *(const uint2*)(h1q + (size_t)s * 256 + o);
        acc8(a, v, hscale[s]);
    }
    if (j < je && half == 0) {
        const int s = srcs[j];
        const uint2 v = *(const uint2*)(h1q + (size_t)s * 256 + o);
        acc8(a, v, hscale[s]);
    }
    #pragma unroll
    for (int k = 0; k < 8; ++k) a[k] += __shfl_down(a[k], 32);
    if (half == 0) {
        uint4 up;
        up.x = (unsigned int)f2bf(a[0]) | ((unsigned int)f2bf(a[1]) << 16);
        up.y = (unsigned int)f2bf(a[2]) | ((unsigned int)f2bf(a[3]) << 16);
        up.z = (unsigned int)f2bf(a[4]) | ((unsigned int)f2bf(a[5]) << 16);
        up.w = (unsigned int)f2bf(a[6]) | ((unsigned int)f2bf(a[7]) << 16);
        *(uint4*)(outb + (size_t)row * S2 + o) = up;
    }
}

// ---------------- layer1: h1q = quant(relu(relu(h1in@w1+b1)@w2+b2)) ----------------
__global__ __launch_bounds__(256) void layer1_fused(
    const short* __restrict__ h1in,   // M x S1 (payload 128)
    const short* __restrict__ w1t,    // 256 x S1
    const float* __restrict__ b1,
    const short* __restrict__ w2t,    // 256 x S2
    const float* __restrict__ b2,
    unsigned char* __restrict__ h1q,  // M x 256 uint8
    float* __restrict__ hscale,       // M
    int M)
{
    __shared__ short sT[64 * S2];
    __shared__ float sMax[64][4];
    __shared__ float sInv[64];
    const int tid  = threadIdx.x;
    const int lane = tid & 63;
    const int wid  = tid >> 6;
    const int r16  = lane & 15;
    const int q    = lane >> 4;
    const int tm   = blockIdx.x * 64;
    const int wn   = wid * 64;

    // ---- stage A: contiguous 64*S1 shorts, coalesced ----
    {
        const short* Aslice = h1in + (size_t)tm * S1;
        #pragma unroll
        for (int c = 0; c < 5; ++c) {
            const int idx = tid + c * 256;
            if (idx < 64 * S1 / 8) {
                const uint4 v = *(const uint4*)(Aslice + idx * 8);
                *(uint4*)(&sT[idx * 8]) = v;
            }
        }
    }
    __syncthreads();

    f32x4 acc[4][4];
    #pragma unroll
    for (int i = 0; i < 4; ++i)
        #pragma unroll
        for (int j = 0; j < 4; ++j)
            acc[i][j] = (f32x4)0.f;

    // ---- GEMM1: K=128, A from LDS ----
    #pragma unroll
    for (int k0 = 0; k0 < 128; k0 += 32) {
        bf16x8 af[4], bfr[4];
        #pragma unroll
        for (int i = 0; i < 4; ++i)
            af[i] = *(const bf16x8*)(&sT[(i * 16 + r16) * S1 + k0 + q * 8]);
        #pragma unroll
        for (int j = 0; j < 4; ++j)
            bfr[j] = *(const bf16x8*)(w1t + (size_t)(wn + j * 16 + r16) * S1 + k0 + q * 8);
        #pragma unroll
        for (int i = 0; i < 4; ++i)
            #pragma unroll
            for (int j = 0; j < 4; ++j)
                acc[i][j] = __builtin_amdgcn_mfma_f32_16x16x32_bf16(af[i], bfr[j], acc[i][j], 0, 0, 0);
    }
    __syncthreads();

    // epilogue1 -> sT (S2 layout)
    #pragma unroll
    for (int j = 0; j < 4; ++j) {
        const int col = wn + j * 16 + r16;
        const float bj = b1[col];
        #pragma unroll
        for (int i = 0; i < 4; ++i)
            #pragma unroll
            for (int r = 0; r < 4; ++r) {
                float v = fmaxf(acc[i][j][r] + bj, 0.f);
                sT[(i * 16 + q * 4 + r) * S2 + col] = (short)f2bf(v);
            }
    }
    __syncthreads();

    // ---- GEMM2: K=256, A from sT ----
    #pragma unroll
    for (int i = 0; i < 4; ++i)
        #pragma unroll
        for (int j = 0; j < 4; ++j)
            acc[i][j] = (f32x4)0.f;

    #pragma unroll
    for (int k0 = 0; k0 < 256; k0 += 32) {
        bf16x8 af[4], bfr[4];
        #pragma unroll
        for (int i = 0; i < 4; ++i)
            af[i] = *(const bf16x8*)(&sT[(i * 16 + r16) * S2 + k0 + q * 8]);
        #pragma unroll
        for (int j = 0; j < 4; ++j)
            bfr[j] = *(const bf16x8*)(w2t + (size_t)(wn + j * 16 + r16) * S2 + k0 + q * 8);
        #pragma unroll
        for (int i = 0; i < 4; ++i)
            #pragma unroll
            for (int j = 0; j < 4; ++j)
                acc[i][j] = __builtin_amdgcn_mfma_f32_16x16x32_bf16(af[i], bfr[j], acc[i][j], 0, 0, 0);
    }
    __syncthreads();

    // epilogue2 -> sT + per-row max (this wave's 64-col slice)
    {
        float bj4[4];
        #pragma unroll
        for (int j = 0; j < 4; ++j) bj4[j] = b2[wn + j * 16 + r16];
        #pragma unroll
        for (int i = 0; i < 4; ++i) {
            #pragma unroll
            for (int r = 0; r < 4; ++r) {
                float m = 0.f;
                #pragma unroll
                for (int j = 0; j < 4; ++j) {
                    float v = fmaxf(acc[i][j][r] + bj4[j], 0.f);
                    sT[(i * 16 + q * 4 + r) * S2 + wn + j * 16 + r16] = (short)f2bf(v);
                    m = fmaxf(m, v);
                }
                #pragma unroll
                for (int off = 1; off < 16; off <<= 1)
                    m = fmaxf(m, __shfl_xor(m, off));
                if (r16 == 0) sMax[i * 16 + q * 4 + r][wid] = m;
            }
        }
    }
    __syncthreads();

    if (tid < 64) {
        const float m = fmaxf(fmaxf(sMax[tid][0], sMax[tid][1]),
                              fmaxf(sMax[tid][2], sMax[tid][3]));
        sInv[tid] = (m > 0.f) ? 255.f / m : 0.f;
        const int rg = tm + tid;
        if (rg < M) hscale[rg] = m * (1.f / 255.f);
    }
    __syncthreads();

    // quantized store: 64 rows x 256 uint8
    #pragma unroll
    for (int c = 0; c < 8; ++c) {
        const int idx = tid + c * 256;
        const int row = idx >> 5;
        const int ch  = idx & 31;
        const int rg  = tm + row;
        if (rg < M) {
            const uint4 v = *(const uint4*)(&sT[row * S2 + ch * 8]);
            const float inv = sInv[row];
            unsigned int q0 = min(255u, (unsigned int)(bflo(v.x) * inv + 0.5f));
            unsigned int q1 = min(255u, (unsigned int)(bfhi(v.x) * inv + 0.5f));
            unsigned int q2 = min(255u, (unsigned int)(bflo(v.y) * inv + 0.5f));
            unsigned int q3 = min(255u, (unsigned int)(bfhi(v.y) * inv + 0.5f));
            unsigned int q4 = min(255u, (unsigned int)(bflo(v.z) * inv + 0.5f));
            unsigned int q5 = min(255u, (unsigned int)(bfhi(v.z) * inv + 0.5f));
            unsigned int q6 = min(255u, (unsigned int)(bflo(v.w) * inv + 0.5f));
            unsigned int q7 = min(255u, (unsigned int)(bfhi(v.w) * inv + 0.5f));
            uint2 o8;
            o8.x = q0 | (q1 << 8) | (q2 << 16) | (q3 << 24);
            o8.y = q4 | (q5 << 8) | (q6 << 16) | (q7 << 24);
            *(uint2*)(h1q + (size_t)rg * 256 + ch * 8) = o8;
        }
    }
}

// ---------------- layer2: out = log_softmax(relu(h2in@w3+b3) @ w4 + b4) ----------------
__global__ __launch_bounds__(256) void layer2_fused(
    const short* __restrict__ h2in,   // M x S2 (payload 256)
    const short* __restrict__ w3t,    // 256 x S2
    const float* __restrict__ b3,
    const float* __restrict__ w4,     // 256 x 2 fp32
    const float* __restrict__ b4,
    float* __restrict__ out,          // M x 2
    int M)
{
    __shared__ short sT[64 * S2];
    const int tid  = threadIdx.x;
    const int lane = tid & 63;
    const int wid  = tid >> 6;
    const int r16  = lane & 15;
    const int q    = lane >> 4;
    const int tm   = blockIdx.x * 64;
    const int wn   = wid * 64;

    {
        const short* Aslice = h2in + (size_t)tm * S2;
        #pragma unroll
        for (int c = 0; c < 9; ++c) {
            const int idx = tid + c * 256;
            if (idx < 64 * S2 / 8) {
                const uint4 v = *(const uint4*)(Aslice + idx * 8);
                *(uint4*)(&sT[idx * 8]) = v;
            }
        }
    }
    __syncthreads();

    f32x4 acc[4][4];
    #pragma unroll
    for (int i = 0; i < 4; ++i)
        #pragma unroll
        for (int j = 0; j < 4; ++j)
            acc[i][j] = (f32x4)0.f;

    #pragma unroll
    for (int k0 = 0; k0 < 256; k0 += 32) {
        bf16x8 af[4], bfr[4];
        #pragma unroll
        for (int i = 0; i < 4; ++i)
            af[i] = *(const bf16x8*)(&sT[(i * 16 + r16) * S2 + k0 + q * 8]);
        #pragma unroll
        for (int j = 0; j < 4; ++j)
            bfr[j] = *(const bf16x8*)(w3t + (size_t)(wn + j * 16 + r16) * S2 + k0 + q * 8);
        #pragma unroll
        for (int i = 0; i < 4; ++i)
            #pragma unroll
            for (int j = 0; j < 4; ++j)
                acc[i][j] = __builtin_amdgcn_mfma_f32_16x16x32_bf16(af[i], bfr[j], acc[i][j], 0, 0, 0);
    }
    __syncthreads();

    #pragma unroll
    for (int j = 0; j < 4; ++j) {
        const int col = wn + j * 16 + r16;
        const float bj = b3[col];
        #pragma unroll
        for (int i = 0; i < 4; ++i)
            #pragma unroll
            for (int r = 0; r < 4; ++r) {
                float v = fmaxf(acc[i][j][r] + bj, 0.f);
                sT[(i * 16 + q * 4 + r) * S2 + col] = (short)f2bf(v);
            }
    }
    __syncthreads();

    const int row = tid >> 2;
    const int qd  = tid & 3;
    const short* tp = &sT[row * S2 + qd * 64];
    const float* w4p = w4 + qd * 128;
    float s0 = 0.f, s1 = 0.f;
    #pragma unroll 8
    for (int k = 0; k < 64; ++k) {
        const float a = bf2f((unsigned short)tp[k]);
        const float2 w = *(const float2*)(w4p + 2 * k);
        s0 = fmaf(a, w.x, s0);
        s1 = fmaf(a, w.y, s1);
    }
    s0 += __shfl_down(s0, 2, 4);  s1 += __shfl_down(s1, 2, 4);
    s0 += __shfl_down(s0, 1, 4);  s1 += __shfl_down(s1, 1, 4);
    if (qd == 0) {
        const int rg = tm + row;
        if (rg < M) {
            s0 += b4[0];
            s1 += b4[1];
            const float m = fmaxf(s0, s1);
            const float l = logf(__expf(s0 - m) + __expf(s1 - m));
            float2 o;
            o.x = s0 - m - l;
            o.y = s1 - m - l;
            *(float2*)(out + (size_t)rg * 2) = o;
        }
    }
}

extern "C" void kernel_launch(void* const* d_in, const int* in_sizes, int n_in,
                              void* d_out, int out_size, void* d_ws, size_t ws_size,
                              hipStream_t stream)
{
    const float* x  = (const float*)d_in[0];
    const int*   ei = (const int*)d_in[1];
    const float* w1 = (const float*)d_in[2];
    const float* b1 = (const float*)d_in[3];
    const float* w2 = (const float*)d_in[4];
    const float* b2 = (const float*)d_in[5];
    const float* w3 = (const float*)d_in[6];
    const float* b3 = (const float*)d_in[7];
    const float* w4 = (const float*)d_in[8];
    const float* b4 = (const float*)d_in[9];

    const int DIN = 128, DH = 256;
    const int M = in_sizes[0] / DIN;   // 50000
    const int E = in_sizes[1] / 2;     // 600000
    const int* src = ei;
    const int* dst = ei + E;
    const int nB = (M + 1023) / 1024;  // <= 64

    // -------- workspace layout --------
    int* deg    = (int*)d_ws;          // M
    int* bsum   = deg + M;             // 64
    int* cur    = bsum + 64;           // M
    int* rowptr = cur + M;             // M+1
    int* srcs   = rowptr + (M + 1);    // E
    size_t off = ((size_t)(3 * M + 1 + 64 + E) * sizeof(int) + 255) & ~(size_t)255;
    unsigned char* x_q = (unsigned char*)((char*)d_ws + off);  off += (size_t)M * 128;  // M x 128 u8
    off = (off + 255) & ~(size_t)255;
    float* xscale = (float*)((char*)d_ws + off);  off += (size_t)M * 4;
    off = (off + 255) & ~(size_t)255;
    short* h1in = (short*)((char*)d_ws + off);  off += (size_t)M * S1 * 2;    // M x 136 bf16
    off = (off + 255) & ~(size_t)255;
    unsigned char* h1q = (unsigned char*)((char*)d_ws + off);  off += (size_t)M * 256; // M x 256 u8
    off = (off + 255) & ~(size_t)255;
    float* hscale = (float*)((char*)d_ws + off);  off += (size_t)M * 4;
    off = (off + 255) & ~(size_t)255;
    short* h2in = (short*)((char*)d_ws + off);  off += (size_t)M * S2 * 2;    // M x 264 bf16
    off = (off + 255) & ~(size_t)255;
    short* w1t  = (short*)((char*)d_ws + off);  off += (size_t)DH * S1 * 2;
    off = (off + 255) & ~(size_t)255;
    short* w2t  = (short*)((char*)d_ws + off);  off += (size_t)DH * S2 * 2;
    off = (off + 255) & ~(size_t)255;
    short* w3t  = (short*)((char*)d_ws + off);  off += (size_t)DH * S2 * 2;

    // -------- prep --------
    hipMemsetAsync(deg, 0, (size_t)M * sizeof(int), stream);
    const int cB = (M * 32 + 255) / 256;
    const int dB = (E + 255) / 256;
    prep_kernel<<<cB + 192 + dB, 256, 0, stream>>>(
        x, x_q, xscale, w1, w2, w3, w1t, w2t, w3t, dst, deg, M, E, cB);

    // -------- CSR build --------
    block_sum_kernel<<<nB, 256, 0, stream>>>(deg, bsum, M);
    scan_blocks2_kernel<<<nB, 256, 0, stream>>>(deg, bsum, rowptr, cur, M, E, nB);
    fill_kernel<<<dB, 256, 0, stream>>>(src, dst, cur, srcs, E);

    const int nblk = (M + 63) / 64;

    // -------- layer 1 --------
    gather_add_d128q<<<(M + 3) / 4, 256, 0, stream>>>(x_q, xscale, rowptr, srcs, h1in, M);
    layer1_fused<<<nblk, 256, 0, stream>>>(h1in, w1t, b1, w2t, b2, h1q, hscale, M);

    // -------- layer 2 --------
    gather_add_d256q<<<(M + 3) / 4, 256, 0, stream>>>(h1q, hscale, rowptr, srcs, h2in, M);
    layer2_fused<<<nblk, 256, 0, stream>>>(h2in, w3t, b3, w4, b4, (float*)d_out, M);
}